// Round 8
// baseline (1711.317 us; speedup 1.0000x reference)
//
#include <hip/hip_runtime.h>
#include <math.h>

#define KTOK 30
#define HIDC 100
#define SB() __builtin_amdgcn_sched_barrier(0)
#define CEXP 0.33554829241286486f

typedef short s16x8 __attribute__((ext_vector_type(8)));
typedef float f32x4 __attribute__((ext_vector_type(4)));

// ---------------------------------------------------------------- helpers
__device__ __forceinline__ unsigned cvt_pk_bf16(float lo, float hi) {
    unsigned r;
    asm("v_cvt_pk_bf16_f32 %0, %1, %2" : "=v"(r) : "v"(lo), "v"(hi));
    return r;
}
__device__ __forceinline__ unsigned short cvt_bf16(float x) {
    unsigned r;
    asm("v_cvt_pk_bf16_f32 %0, %1, 0" : "=v"(r) : "v"(x));
    return (unsigned short)r;
}
__device__ __forceinline__ float bf2f(unsigned short h) {
    return __uint_as_float(((unsigned)h) << 16);
}
__device__ __forceinline__ float exp2_fast(float x) {
    float r;
    asm("v_exp_f32 %0, %1" : "=v"(r) : "v"(x));
    return r;
}
__device__ __forceinline__ float cos_rev(float rev) {   // input in revolutions, |rev|<1
    float r;
    asm("v_cos_f32 %0, %1" : "=v"(r) : "v"(rev));
    return r;
}
__device__ __forceinline__ unsigned short f2bf(float f) {
    unsigned u = __float_as_uint(f);
    unsigned r = (u + 0x7FFFu + ((u >> 16) & 1u)) >> 16;
    return (unsigned short)r;
}
// tanh-form GELU, log2e folded: x / (1 + 2^(-x*(c1+c2*x^2)))
__device__ __forceinline__ float gelu(float x) {
    float s = x * x;
    float t = fmaf(s, 0.10294334f, 2.3022082f);
    float e = exp2_fast(-x * t);
    return x * __builtin_amdgcn_rcpf(1.0f + e);
}

// ---------------------------------------------------------------- selection pipeline
__global__ void count_kernel(const int* __restrict__ nb, int* __restrict__ cnt, int E) {
    int e = blockIdx.x * blockDim.x + threadIdx.x;
    if (e < E) atomicAdd(&cnt[nb[e]], 1);
}

__global__ void scanA_kernel(const int* __restrict__ cnt, int* __restrict__ offsets,
                             int* __restrict__ bsum, int n) {
    __shared__ int sd[1024];
    int tid = threadIdx.x;
    int i = blockIdx.x * 1024 + tid;
    int v = (i < n) ? cnt[i] : 0;
    sd[tid] = v;
    __syncthreads();
    for (int off = 1; off < 1024; off <<= 1) {
        int tv = (tid >= off) ? sd[tid - off] : 0;
        __syncthreads();
        sd[tid] += tv;
        __syncthreads();
    }
    if (i < n) offsets[i] = sd[tid] - v;            // block-local exclusive
    if (tid == 1023) bsum[blockIdx.x] = sd[1023];   // block total
}

__global__ void scanB_kernel(int* __restrict__ bsum, int nbk) {
    if (threadIdx.x == 0 && blockIdx.x == 0) {
        int run = 0;
        for (int b = 0; b < nbk; b++) { int tv = bsum[b]; bsum[b] = run; run += tv; }
    }
}

__global__ void scanC_kernel(int* __restrict__ offsets, const int* __restrict__ bsum, int n) {
    int i = blockIdx.x * blockDim.x + threadIdx.x;
    if (i < n) offsets[i] += bsum[i >> 10];
}

__global__ void fill_kernel(const int* __restrict__ nb, int* __restrict__ cursor,
                            const int* __restrict__ offsets, int* __restrict__ order, int E) {
    int e = blockIdx.x * blockDim.x + threadIdx.x;
    if (e >= E) return;
    int n = nb[e];
    int p = atomicAdd(&cursor[n], 1);
    order[offsets[n] + p] = e;
}

__global__ void select_kernel(const int* __restrict__ cnt, const int* __restrict__ offsets,
                              const int* __restrict__ order, int* __restrict__ sel, int N) {
    int node = blockIdx.x * blockDim.x + threadIdx.x;
    if (node >= N) return;
    int c = cnt[node];
    int off = offsets[node];
    int top[KTOK];
    int m = 0;
    for (int i = 0; i < c; i++) {
        int e = order[off + i];
        if (m < KTOK) {
            int j = m++;
            while (j > 0 && top[j - 1] > e) { top[j] = top[j - 1]; j--; }
            top[j] = e;
        } else if (e < top[KTOK - 1]) {
            int j = KTOK - 1;
            while (j > 0 && top[j - 1] > e) { top[j] = top[j - 1]; j--; }
            top[j] = e;
        }
    }
    for (int p = 0; p < KTOK; p++) sel[node * KTOK + p] = (p < m) ? top[p] : -1;
}

// ---------------------------------------------------------------- weight fragment prep
// B-frag (16x16x32): lane l elem i holds B[kt*32+(l>>4)*8+i][nt*16+(l&15)]
// wf: headWf[8][7][64][8]@0 ; wg1f(=ch1_w*ln_c_g)[4][25][64][8]@28672 ;
//     w2f[13][7][64][8]@79872 ; tok1f[64][8]@126464 ; tok2f[2][64][8]@126976
// extras (f32): Sg1[400] = sum_k ch1_w*g ; b1p[400] = sum_k ch1_w*b + ch1_b
__global__ void prep_kernel(const float* __restrict__ head_w, const float* __restrict__ ch1_w,
                            const float* __restrict__ ch2_w, const float* __restrict__ tok1_w,
                            const float* __restrict__ tok2_w,
                            const float* __restrict__ ln_c_g, const float* __restrict__ ln_c_b,
                            const float* __restrict__ ch1_b,
                            unsigned short* __restrict__ wf,
                            float* __restrict__ Sg1, float* __restrict__ b1p) {
    int i = blockIdx.x * blockDim.x + threadIdx.x;
    if (i >= 128000) {
        int h = i - 128000;
        if (h < 400) {
            float sg = 0.f, sb = 0.f;
            for (int k = 0; k < 100; k++) {
                float w = ch1_w[h * 100 + k];
                sg += w * ln_c_g[k];
                sb += w * ln_c_b[k];
            }
            Sg1[h] = sg;
            b1p[h] = sb + ch1_b[h];
        }
        return;
    }
    float val = 0.0f;
    if (i < 28672) {
        int ii = i & 7, lane = (i >> 3) & 63, rest = i >> 9;
        int nt = rest % 7, kt = rest / 7;
        int k = kt * 32 + ((lane >> 4) << 3) + ii;
        int n = nt * 16 + (lane & 15);
        if (k < 200 && n < 100) val = head_w[n * 200 + k];
    } else if (i < 79872) {
        int j = i - 28672;
        int ii = j & 7, lane = (j >> 3) & 63, rest = j >> 9;
        int nt = rest % 25, kt = rest / 25;
        int k = kt * 32 + ((lane >> 4) << 3) + ii;
        int n = nt * 16 + (lane & 15);
        if (k < 100) val = ch1_w[n * 100 + k] * ln_c_g[k];
    } else if (i < 126464) {
        int j = i - 79872;
        int ii = j & 7, lane = (j >> 3) & 63, rest = j >> 9;
        int nt = rest % 7, kt = rest / 7;
        int k = kt * 32 + ((lane >> 4) << 3) + ii;
        int n = nt * 16 + (lane & 15);
        if (k < 400 && n < 100) val = ch2_w[n * 400 + k];
    } else if (i < 126976) {
        int j = i - 126464;
        int ii = j & 7, lane = (j >> 3) & 63;
        int k = ((lane >> 4) << 3) + ii;
        int n = lane & 15;
        if (k < 30 && n < 15) val = tok1_w[n * 30 + k];
    } else {
        int j = i - 126976;
        int ii = j & 7, lane = (j >> 3) & 63, nt = j >> 9;
        int k = ((lane >> 4) << 3) + ii;
        int n = nt * 16 + (lane & 15);
        if (k < 15 && n < 30) val = tok2_w[n * 15 + k];
    }
    wf[i] = f2bf(val);
}

// ---------------------------------------------------------------- fused per-node forward
// 2 nodes/block, 1 wave/node, zero __syncthreads. LDS/block ~18.4KB -> 8 blocks/CU.
// All LNs register-based; LN_c folded into prepped ch1 weights.
__global__ __launch_bounds__(128, 4) void fused_node_kernel(
    const float* __restrict__ edge_attr, const float* __restrict__ edge_time,
    const int* __restrict__ sel, const unsigned short* __restrict__ wf,
    const float* __restrict__ head_b,
    const float* __restrict__ ln_t_g, const float* __restrict__ ln_t_b,
    const float* __restrict__ tok1_b, const float* __restrict__ tok2_b,
    const float* __restrict__ Sg1, const float* __restrict__ b1p,
    const float* __restrict__ ch2_b,
    const float* __restrict__ ln_h_g, const float* __restrict__ ln_h_b,
    const float* __restrict__ out_w, const float* __restrict__ out_b,
    float* __restrict__ out, int N) {

    __shared__ __align__(16) unsigned short xb2[2][32 * 104];  // x -> h_token (6656 B/wave)
    __shared__ __align__(16) unsigned short scr2[2][1280];     // av-batches / y / cbw / stF (2560 B/wave)

    const int t = threadIdx.x;
    const int wv = t >> 6, l = t & 63;
    const int g = l >> 4, c16 = l & 15;
    unsigned short* xbw = xb2[wv];
    unsigned short* scrw = scr2[wv];
    char* scrb = (char*)scrw;
    const int node = blockIdx.x * 2 + wv;

    const s16x8 zfrag = {0, 0, 0, 0, 0, 0, 0, 0};
    const f32x4 zacc = {0.f, 0.f, 0.f, 0.f};

    const s16x8* headWf_v = (const s16x8*)(wf);
    const s16x8* wg1f_v   = (const s16x8*)(wf + 28672);
    const s16x8* w2f_v    = (const s16x8*)(wf + 79872);
    const s16x8* tok1f_v  = (const s16x8*)(wf + 126464);
    const s16x8* tok2f_v  = (const s16x8*)(wf + 126976);

    // ---- per-lane edge info (no LDS)
    int eload = (l < KTOK && node < N) ? sel[node * KTOK + l] : -1;
    unsigned long long vmask = __ballot(eload >= 0);   // bit r = validity of token row r
    int e0 = __shfl(eload, c16);
    int e1 = __shfl(eload, 16 + c16);
    float tt0 = (e0 >= 0) ? edge_time[e0] : 0.f;
    float tt1 = (e1 >= 0) ? edge_time[e1] : 0.f;
    const float INV2PI = 0.15915494309189535f;
    float Trev0 = tt0 * INV2PI, Trev1 = tt1 * INV2PI;
    const float* ab0 = edge_attr + (size_t)(e0 < 0 ? 0 : e0) * 100;
    const float* ab1 = edge_attr + (size_t)(e1 < 0 ? 0 : e1) * 100;

    // ---- cached per-lane coefficients (col = nt*16 + c16, clamped)
    float g7[7], b7[7], hb7[7];
    #pragma unroll
    for (int nt = 0; nt < 7; nt++) {
        int cc = nt * 16 + c16; if (cc > 99) cc = 99;
        g7[nt] = ln_t_g[cc]; b7[nt] = ln_t_b[cc]; hb7[nt] = head_b[cc];
    }

    // ================= Phase A: head GEMM, A-frags built in registers =================
    f32x4 hacc[2][7];
    #pragma unroll
    for (int a = 0; a < 2; a++)
        #pragma unroll
        for (int c = 0; c < 7; c++) hacc[a][c] = zacc;

    #pragma unroll
    for (int kc = 0; kc < 4; kc++) {
        s16x8 af[2][2];
        #pragma unroll
        for (int mt = 0; mt < 2; mt++) {
            const float Trev = mt ? Trev1 : Trev0;
            const float* abm = mt ? ab1 : ab0;
            #pragma unroll
            for (int kk = 0; kk < 2; kk++) {
                const int kb0 = kc * 64 + kk * 32;   // compile-time
                union { s16x8 v; unsigned u[4]; } r;
                if (kb0 + 32 <= 100) {
                    // pure temporal: IN[k] = cos(t * rho^k), rho^k in revolutions
                    float Ab = Trev * exp2_fast(-CEXP * (float)(kb0 + g * 8));
                    #pragma unroll
                    for (int i2 = 0; i2 < 8; i2 += 2) {
                        float v0 = cos_rev(Ab * exp2f(-CEXP * (float)i2));
                        float v1 = cos_rev(Ab * exp2f(-CEXP * (float)(i2 + 1)));
                        r.u[i2 >> 1] = cvt_pk_bf16(v0, v1);
                    }
                } else if (kb0 == 96) {
                    // mixed: g0 has k 96..103 (4 cos + 4 attr), g>=1 all attr
                    int aoff = kb0 + g * 8 - 100;
                    int ac = aoff < 0 ? 0 : aoff;           // multiples of 4 -> aligned
                    const float* ap = abm + ac;
                    float4 A0 = *(const float4*)ap;
                    float4 A1 = *(const float4*)(ap + 4);
                    float fa[8] = {A0.x, A0.y, A0.z, A0.w, A1.x, A1.y, A1.z, A1.w};
                    float Ab = Trev * exp2_fast(-CEXP * (float)(kb0 + g * 8));
                    #pragma unroll
                    for (int i2 = 0; i2 < 8; i2 += 2) {
                        float cc0 = cos_rev(Ab * exp2f(-CEXP * (float)i2));
                        float cc1 = cos_rev(Ab * exp2f(-CEXP * (float)(i2 + 1)));
                        float a0 = (g == 0) ? ((i2 >= 4) ? fa[(i2 >= 4) ? i2 - 4 : 0] : 0.f) : fa[i2];
                        float a1 = (g == 0) ? ((i2 + 1 >= 4) ? fa[(i2 + 1 >= 4) ? i2 - 3 : 0] : 0.f) : fa[i2 + 1];
                        int k0 = kb0 + g * 8 + i2;
                        float v0 = (k0 < 100) ? cc0 : a0;
                        float v1 = (k0 + 1 < 100) ? cc1 : a1;
                        r.u[i2 >> 1] = cvt_pk_bf16(v0, v1);
                    }
                } else if (kb0 <= 160) {
                    // pure attr
                    int ac = kb0 + g * 8 - 100;
                    const float* ap = abm + ac;
                    float4 A0 = *(const float4*)ap;
                    float4 A1 = *(const float4*)(ap + 4);
                    r.u[0] = cvt_pk_bf16(A0.x, A0.y);
                    r.u[1] = cvt_pk_bf16(A0.z, A0.w);
                    r.u[2] = cvt_pk_bf16(A1.x, A1.y);
                    r.u[3] = cvt_pk_bf16(A1.z, A1.w);
                } else if (kb0 == 192) {
                    // attr tail + zeros (k>=200)
                    int aoff = kb0 + g * 8 - 100;
                    int ac = aoff > 92 ? 92 : aoff;
                    const float* ap = abm + ac;
                    float4 A0 = *(const float4*)ap;
                    float4 A1 = *(const float4*)(ap + 4);
                    float fa[8] = {A0.x, A0.y, A0.z, A0.w, A1.x, A1.y, A1.z, A1.w};
                    #pragma unroll
                    for (int i2 = 0; i2 < 8; i2 += 2) {
                        int k0 = kb0 + g * 8 + i2;
                        float v0 = (k0 < 200) ? fa[i2] : 0.f;
                        float v1 = (k0 + 1 < 200) ? fa[i2 + 1] : 0.f;
                        r.u[i2 >> 1] = cvt_pk_bf16(v0, v1);
                    }
                } else {
                    r.u[0] = 0; r.u[1] = 0; r.u[2] = 0; r.u[3] = 0;
                }
                af[mt][kk] = r.v;
            }
        }
        #pragma unroll
        for (int nt = 0; nt < 7; nt++) {
            #pragma unroll
            for (int kk = 0; kk < 2; kk++) {
                s16x8 bf = headWf_v[((kc * 2 + kk) * 7 + nt) * 64 + l];
                #pragma unroll
                for (int mt = 0; mt < 2; mt++)
                    hacc[mt][nt] = __builtin_amdgcn_mfma_f32_16x16x32_bf16(af[mt][kk], bf, hacc[mt][nt], 0, 0, 0);
            }
        }
    }

    // ---- x = mask(hacc + bias); rows with sel<0 and cols>=100 are exact 0
    #pragma unroll
    for (int mt = 0; mt < 2; mt++)
        #pragma unroll
        for (int nt = 0; nt < 7; nt++)
            #pragma unroll
            for (int jj = 0; jj < 4; jj++) {
                int row = mt * 16 + g * 4 + jj;
                bool ok = (((vmask >> row) & 1ull) != 0) && (nt < 6 || c16 < 4);
                hacc[mt][nt][jj] = ok ? (hacc[mt][nt][jj] + hb7[nt]) : 0.f;
            }

    // ---- x-store to xbw [32][104] (+ zero pad cols 100..103)
    #pragma unroll
    for (int mt = 0; mt < 2; mt++)
        #pragma unroll
        for (int nt = 0; nt < 7; nt++)
            #pragma unroll
            for (int jj = 0; jj < 4; jj++) {
                int row = mt * 16 + g * 4 + jj;
                int col = nt * 16 + c16;
                if (col < 100)      xbw[row * 104 + col] = cvt_bf16(hacc[mt][nt][jj]);
                else if (col < 104) xbw[row * 104 + col] = 0;
            }

    // ---- LN_t stats per row (reduce over 16 col-lanes)
    float mv[2][4], rv[2][4];
    #pragma unroll
    for (int mt = 0; mt < 2; mt++)
        #pragma unroll
        for (int jj = 0; jj < 4; jj++) {
            float s = 0.f, s2 = 0.f;
            #pragma unroll
            for (int nt = 0; nt < 7; nt++) {
                float v = hacc[mt][nt][jj];
                s += v;
                s2 = fmaf(v, v, s2);
            }
            #pragma unroll
            for (int msk = 1; msk < 16; msk <<= 1) {
                s  += __shfl_xor(s, msk);
                s2 += __shfl_xor(s2, msk);
            }
            float m = s * 0.01f;
            float var = fmaxf(s2 * 0.01f - m * m, 0.f);
            mv[mt][jj] = m;
            rv[mt][jj] = rsqrtf(var + 1e-5f);
        }

    // ---- scatter normalized LN_t into A-slot layout (2-nt batches), read av A-frags
    // slot addr for value (ch,tok): (ch>>4 region) + ((ch&15)+(tok>>3)*16)*8 + (tok&7)
    s16x8 av[7];
    #pragma unroll
    for (int nb = 0; nb < 4; nb++) {
        #pragma unroll
        for (int nn = 0; nn < 2; nn++) {
            int nt = nb * 2 + nn;
            if (nt < 7) {
                #pragma unroll
                for (int mt = 0; mt < 2; mt++) {
                    float h0 = fmaf((hacc[mt][nt][0] - mv[mt][0]) * rv[mt][0], g7[nt], b7[nt]);
                    float h1 = fmaf((hacc[mt][nt][1] - mv[mt][1]) * rv[mt][1], g7[nt], b7[nt]);
                    float h2 = fmaf((hacc[mt][nt][2] - mv[mt][2]) * rv[mt][2], g7[nt], b7[nt]);
                    float h3 = fmaf((hacc[mt][nt][3] - mv[mt][3]) * rv[mt][3], g7[nt], b7[nt]);
                    unsigned w0 = cvt_pk_bf16(h0, h1);
                    unsigned w1 = cvt_pk_bf16(h2, h3);
                    int ba = (nt & 1) * 1024 + (c16 + 32 * mt + 16 * (g >> 1)) * 16 + 8 * (g & 1);
                    *(uint2*)(scrb + ba) = make_uint2(w0, w1);
                }
            }
        }
        SB();
        #pragma unroll
        for (int nn = 0; nn < 2; nn++) {
            int nt = nb * 2 + nn;
            if (nt < 7)
                av[nt] = *(const s16x8*)(scrb + (nt & 1) * 1024 + l * 16);
        }
        SB();
    }

    // ================= Phase B: token mixer (per ch-tile; y via slot buffer) =================
    {
        s16x8 b1 = tok1f_v[l];
        float bias1 = (c16 < 15) ? tok1_b[c16] : 0.f;
        s16x8 b2a = tok2f_v[l];
        s16x8 b2b = tok2f_v[64 + l];
        float tb0 = tok2_b[c16];
        float tb1 = (c16 < 14) ? tok2_b[16 + c16] : 0.f;
        #pragma unroll
        for (int mt7 = 0; mt7 < 7; mt7++) {
            f32x4 y = __builtin_amdgcn_mfma_f32_16x16x32_bf16(av[mt7], b1, zacc, 0, 0, 0);
            #pragma unroll
            for (int jj = 0; jj < 4; jj++) {
                int ba = ((g * 4 + jj) + (c16 >> 3) * 16) * 16 + (c16 & 7) * 2;
                *(unsigned short*)(scrb + ba) = cvt_bf16(gelu(y[jj] + bias1));
            }
            SB();
            s16x8 a2 = zfrag;
            if (g < 2) a2 = *(const s16x8*)(scrb + l * 16);
            SB();
            f32x4 d0 = __builtin_amdgcn_mfma_f32_16x16x32_bf16(a2, b2a, zacc, 0, 0, 0);
            f32x4 d1 = __builtin_amdgcn_mfma_f32_16x16x32_bf16(a2, b2b, zacc, 0, 0, 0);
            #pragma unroll
            for (int jj = 0; jj < 4; jj++) {
                int chD = mt7 * 16 + g * 4 + jj;
                if (chD < 100) {
                    int idx0 = c16 * 104 + chD;
                    xbw[idx0] = cvt_bf16(bf2f(xbw[idx0]) + d0[jj] + tb0);
                    int tok1i = 16 + c16;
                    if (tok1i < 30) {
                        int idx1 = tok1i * 104 + chD;
                        xbw[idx1] = cvt_bf16(bf2f(xbw[idx1]) + d1[jj] + tb1);
                    }
                }
            }
            SB();
        }
    }

    // ================= Phase C: ch1 (LN_c folded) -> gelu -> ch2 =================
    unsigned short* cbw = scrw;   // [32][40] u16 ping buffer
    f32x4 acc2[2][7];
    {
        s16x8 a1f[2][4];
        #pragma unroll
        for (int mt = 0; mt < 2; mt++)
            #pragma unroll
            for (int kk = 0; kk < 4; kk++) {
                s16x8 a = zfrag;
                if (kk < 3 || g == 0)
                    a = *(const s16x8*)&xbw[(mt * 16 + c16) * 104 + kk * 32 + g * 8];
                a1f[mt][kk] = a;
            }
        SB();

        // LN_c stats from raw h_token (a1f regs): per tok = c16 (within mt tile)
        float rs_r[2][4], rm_r[2][4];
        {
            float mA[2], rA[2];
            #pragma unroll
            for (int mt = 0; mt < 2; mt++) {
                float s = 0.f, s2 = 0.f;
                #pragma unroll
                for (int kk = 0; kk < 4; kk++)
                    #pragma unroll
                    for (int i = 0; i < 8; i++) {
                        float f = bf2f((unsigned short)a1f[mt][kk][i]);
                        s += f;
                        s2 = fmaf(f, f, s2);
                    }
                s  += __shfl_xor(s, 16);  s  += __shfl_xor(s, 32);
                s2 += __shfl_xor(s2, 16); s2 += __shfl_xor(s2, 32);
                float m = s * 0.01f;
                float var = fmaxf(s2 * 0.01f - m * m, 0.f);
                mA[mt] = m;
                rA[mt] = rsqrtf(var + 1e-5f);
            }
            #pragma unroll
            for (int mt = 0; mt < 2; mt++)
                #pragma unroll
                for (int jj = 0; jj < 4; jj++) {
                    int src = g * 4 + jj;
                    float mm = __shfl(mA[mt], src);
                    float rr = __shfl(rA[mt], src);
                    rs_r[mt][jj] = rr;
                    rm_r[mt][jj] = rr * mm;
                }
        }

        #pragma unroll
        for (int a = 0; a < 2; a++)
            #pragma unroll
            for (int c = 0; c < 7; c++) acc2[a][c] = zacc;

        for (int hc = 0; hc < 13; hc++) {
            f32x4 acc1[2][2];
            float Sg[2], Bp[2];
            #pragma unroll
            for (int a = 0; a < 2; a++) { acc1[a][0] = zacc; acc1[a][1] = zacc; }
            #pragma unroll
            for (int ntl = 0; ntl < 2; ntl++) {
                int ntg = hc * 2 + ntl;
                if (ntg < 25) {
                    int h = ntg * 16 + c16;
                    Sg[ntl] = Sg1[h];
                    Bp[ntl] = b1p[h];
                    #pragma unroll
                    for (int kk = 0; kk < 4; kk++) {
                        s16x8 bfr = wg1f_v[(kk * 25 + ntg) * 64 + l];
                        #pragma unroll
                        for (int mt = 0; mt < 2; mt++)
                            acc1[mt][ntl] = __builtin_amdgcn_mfma_f32_16x16x32_bf16(a1f[mt][kk], bfr, acc1[mt][ntl], 0, 0, 0);
                    }
                }
            }
            #pragma unroll
            for (int ntl = 0; ntl < 2; ntl++) {
                int ntg = hc * 2 + ntl;
                if (ntg < 25) {
                    #pragma unroll
                    for (int mt = 0; mt < 2; mt++)
                        #pragma unroll
                        for (int jj = 0; jj < 4; jj++) {
                            int row = mt * 16 + g * 4 + jj;
                            float h1 = fmaf(rs_r[mt][jj], acc1[mt][ntl][jj],
                                            fmaf(-rm_r[mt][jj], Sg[ntl], Bp[ntl]));
                            cbw[row * 40 + ntl * 16 + c16] = cvt_bf16(gelu(h1));
                        }
                }
            }
            SB();
            s16x8 a2f[2];
            #pragma unroll
            for (int mt = 0; mt < 2; mt++)
                a2f[mt] = *(const s16x8*)&cbw[(mt * 16 + c16) * 40 + g * 8];
            SB();
            #pragma unroll
            for (int nt2 = 0; nt2 < 7; nt2++) {
                s16x8 b2f = w2f_v[(hc * 7 + nt2) * 64 + l];
                #pragma unroll
                for (int mt = 0; mt < 2; mt++)
                    acc2[mt][nt2] = __builtin_amdgcn_mfma_f32_16x16x32_bf16(a2f[mt], b2f, acc2[mt][nt2], 0, 0, 0);
            }
            SB();
        }
    }

    // ================= Phase D: h_channel -> LN_h -> mean -> out proj (registers) =================
    #pragma unroll
    for (int nt = 0; nt < 7; nt++) {
        int col = nt * 16 + c16;
        if (col < 100) {
            float bias = ch2_b[col];
            #pragma unroll
            for (int mt = 0; mt < 2; mt++)
                #pragma unroll
                for (int jj = 0; jj < 4; jj++) {
                    int row = mt * 16 + g * 4 + jj;
                    acc2[mt][nt][jj] += bias + bf2f(xbw[row * 104 + col]);
                }
        }
    }
    float m_[2][4], rs_[2][4];
    #pragma unroll
    for (int mt = 0; mt < 2; mt++)
        #pragma unroll
        for (int jj = 0; jj < 4; jj++) {
            float s = 0.f, s2 = 0.f;
            #pragma unroll
            for (int nt = 0; nt < 7; nt++) {
                float v = acc2[mt][nt][jj];
                s += v;
                s2 = fmaf(v, v, s2);
            }
            #pragma unroll
            for (int msk = 1; msk < 16; msk <<= 1) {
                s  += __shfl_xor(s, msk);
                s2 += __shfl_xor(s2, msk);
            }
            float m = s * 0.01f;
            float var = fmaxf(s2 * 0.01f - m * m, 0.f);
            m_[mt][jj]  = m;
            rs_[mt][jj] = rsqrtf(var + 1e-5f);
        }
    float cs[7];
    #pragma unroll
    for (int nt = 0; nt < 7; nt++) cs[nt] = 0.f;
    #pragma unroll
    for (int mt = 0; mt < 2; mt++)
        #pragma unroll
        for (int jj = 0; jj < 4; jj++) {
            int row = mt * 16 + g * 4 + jj;
            if (row < 30) {
                float m = m_[mt][jj], rs = rs_[mt][jj];
                #pragma unroll
                for (int nt = 0; nt < 7; nt++)
                    cs[nt] = fmaf(acc2[mt][nt][jj] - m, rs, cs[nt]);
            }
        }
    #pragma unroll
    for (int nt = 0; nt < 7; nt++) {
        cs[nt] += __shfl_xor(cs[nt], 16);
        cs[nt] += __shfl_xor(cs[nt], 32);
    }
    float* stF = (float*)scrw;     // cbw dead
    if (g == 0) {
        #pragma unroll
        for (int nt = 0; nt < 7; nt++) {
            int col = nt * 16 + c16;
            if (col < 100)
                stF[col] = ln_h_g[col] * cs[nt] * (1.0f / 30.0f) + ln_h_b[col];
        }
    }
    SB();
    #pragma unroll
    for (int p = 0; p < 2; p++) {
        int o = p * 64 + l;
        if (o < 100 && node < N) {
            float a = out_b[o];
            const float* wr = out_w + o * 100;
            #pragma unroll
            for (int c = 0; c < 100; c += 4) {
                float4 w4 = *(const float4*)(wr + c);
                f32x4 t4 = *(const f32x4*)&stF[c];
                a += w4.x * t4[0] + w4.y * t4[1] + w4.z * t4[2] + w4.w * t4[3];
            }
            out[(size_t)node * 100 + o] = a;
        }
    }
}

// ---------------------------------------------------------------- launch

extern "C" void kernel_launch(void* const* d_in, const int* in_sizes, int n_in,
                              void* d_out, int out_size, void* d_ws, size_t ws_size,
                              hipStream_t stream) {
    const float* edge_attr  = (const float*)d_in[0];
    const float* edge_time  = (const float*)d_in[1];
    const int*   node_batch = (const int*)d_in[2];
    const float* head_w = (const float*)d_in[4];
    const float* head_b = (const float*)d_in[5];
    const float* ln_t_g = (const float*)d_in[6];
    const float* ln_t_b = (const float*)d_in[7];
    const float* tok1_w = (const float*)d_in[8];
    const float* tok1_b = (const float*)d_in[9];
    const float* tok2_w = (const float*)d_in[10];
    const float* tok2_b = (const float*)d_in[11];
    const float* ln_c_g = (const float*)d_in[12];
    const float* ln_c_b = (const float*)d_in[13];
    const float* ch1_w  = (const float*)d_in[14];
    const float* ch1_b  = (const float*)d_in[15];
    const float* ch2_w  = (const float*)d_in[16];
    const float* ch2_b  = (const float*)d_in[17];
    const float* ln_h_g = (const float*)d_in[18];
    const float* ln_h_b = (const float*)d_in[19];
    const float* out_w  = (const float*)d_in[20];
    const float* out_b  = (const float*)d_in[21];
    float* out = (float*)d_out;

    const int E = in_sizes[2];
    const int N = out_size / HIDC;

    int* cnt     = (int*)d_ws;                            // N
    int* cursor  = cnt + N;                               // N
    int* offsets = cursor + N;                            // N
    int* order   = offsets + N;                           // E
    int* sel     = order + E;                             // N*K
    unsigned short* wf = (unsigned short*)(sel + (size_t)N * KTOK);  // 128000 u16
    float* Sg1 = (float*)(wf + 128000);                   // 400
    float* b1p = Sg1 + 400;                               // 400
    int*   bsum = (int*)(b1p + 400);                      // <=64

    const int nbk = (N + 1023) / 1024;

    hipMemsetAsync(cnt, 0, (size_t)2 * N * sizeof(int), stream);
    count_kernel<<<(E + 255) / 256, 256, 0, stream>>>(node_batch, cnt, E);
    scanA_kernel<<<nbk, 1024, 0, stream>>>(cnt, offsets, bsum, N);
    scanB_kernel<<<1, 64, 0, stream>>>(bsum, nbk);
    scanC_kernel<<<(N + 255) / 256, 256, 0, stream>>>(offsets, bsum, N);
    fill_kernel<<<(E + 255) / 256, 256, 0, stream>>>(node_batch, cursor, offsets, order, E);
    select_kernel<<<(N + 255) / 256, 256, 0, stream>>>(cnt, offsets, order, sel, N);
    prep_kernel<<<502, 256, 0, stream>>>(head_w, ch1_w, ch2_w, tok1_w, tok2_w,
                                         ln_c_g, ln_c_b, ch1_b, wf, Sg1, b1p);
    fused_node_kernel<<<(N + 1) / 2, 128, 0, stream>>>(
        edge_attr, edge_time, sel, wf, head_b,
        ln_t_g, ln_t_b, tok1_b, tok2_b, Sg1, b1p,
        ch2_b, ln_h_g, ln_h_b, out_w, out_b, out, N);
}

// Round 9
// 1131.558 us; speedup vs baseline: 1.5124x; 1.5124x over previous
//
#include <hip/hip_runtime.h>
#include <math.h>

#define KTOK 30
#define HIDC 100
#define SB() __builtin_amdgcn_sched_barrier(0)
#define CEXP 0.33554829241286486f

typedef short s16x8 __attribute__((ext_vector_type(8)));
typedef float f32x4 __attribute__((ext_vector_type(4)));

// ---------------------------------------------------------------- helpers
__device__ __forceinline__ unsigned cvt_pk_bf16(float lo, float hi) {
    unsigned r;
    asm("v_cvt_pk_bf16_f32 %0, %1, %2" : "=v"(r) : "v"(lo), "v"(hi));
    return r;
}
__device__ __forceinline__ unsigned short cvt_bf16(float x) {
    unsigned r;
    asm("v_cvt_pk_bf16_f32 %0, %1, 0" : "=v"(r) : "v"(x));
    return (unsigned short)r;
}
__device__ __forceinline__ float bf2f(unsigned short h) {
    return __uint_as_float(((unsigned)h) << 16);
}
__device__ __forceinline__ float exp2_fast(float x) {
    float r;
    asm("v_exp_f32 %0, %1" : "=v"(r) : "v"(x));
    return r;
}
__device__ __forceinline__ float cos_rev(float rev) {   // input in revolutions, |rev|<1
    float r;
    asm("v_cos_f32 %0, %1" : "=v"(r) : "v"(rev));
    return r;
}
__device__ __forceinline__ unsigned short f2bf(float f) {
    unsigned u = __float_as_uint(f);
    unsigned r = (u + 0x7FFFu + ((u >> 16) & 1u)) >> 16;
    return (unsigned short)r;
}
// tanh-form GELU, log2e folded: x / (1 + 2^(-x*(c1+c2*x^2)))
__device__ __forceinline__ float gelu(float x) {
    float s = x * x;
    float t = fmaf(s, 0.10294334f, 2.3022082f);
    float e = exp2_fast(-x * t);
    return x * __builtin_amdgcn_rcpf(1.0f + e);
}

// ---------------------------------------------------------------- selection pipeline
__global__ void count_kernel(const int* __restrict__ nb, int* __restrict__ cnt, int E) {
    int e = blockIdx.x * blockDim.x + threadIdx.x;
    if (e < E) atomicAdd(&cnt[nb[e]], 1);
}

__global__ void scanA_kernel(const int* __restrict__ cnt, int* __restrict__ offsets,
                             int* __restrict__ bsum, int n) {
    __shared__ int sd[1024];
    int tid = threadIdx.x;
    int i = blockIdx.x * 1024 + tid;
    int v = (i < n) ? cnt[i] : 0;
    sd[tid] = v;
    __syncthreads();
    for (int off = 1; off < 1024; off <<= 1) {
        int tv = (tid >= off) ? sd[tid - off] : 0;
        __syncthreads();
        sd[tid] += tv;
        __syncthreads();
    }
    if (i < n) offsets[i] = sd[tid] - v;            // block-local exclusive
    if (tid == 1023) bsum[blockIdx.x] = sd[1023];   // block total
}

__global__ void scanB_kernel(int* __restrict__ bsum, int nbk) {
    if (threadIdx.x == 0 && blockIdx.x == 0) {
        int run = 0;
        for (int b = 0; b < nbk; b++) { int tv = bsum[b]; bsum[b] = run; run += tv; }
    }
}

__global__ void scanC_kernel(int* __restrict__ offsets, const int* __restrict__ bsum, int n) {
    int i = blockIdx.x * blockDim.x + threadIdx.x;
    if (i < n) offsets[i] += bsum[i >> 10];
}

__global__ void fill_kernel(const int* __restrict__ nb, int* __restrict__ cursor,
                            const int* __restrict__ offsets, int* __restrict__ order, int E) {
    int e = blockIdx.x * blockDim.x + threadIdx.x;
    if (e >= E) return;
    int n = nb[e];
    int p = atomicAdd(&cursor[n], 1);
    order[offsets[n] + p] = e;
}

__global__ void select_kernel(const int* __restrict__ cnt, const int* __restrict__ offsets,
                              const int* __restrict__ order, int* __restrict__ sel, int N) {
    int node = blockIdx.x * blockDim.x + threadIdx.x;
    if (node >= N) return;
    int c = cnt[node];
    int off = offsets[node];
    int top[KTOK];
    int m = 0;
    for (int i = 0; i < c; i++) {
        int e = order[off + i];
        if (m < KTOK) {
            int j = m++;
            while (j > 0 && top[j - 1] > e) { top[j] = top[j - 1]; j--; }
            top[j] = e;
        } else if (e < top[KTOK - 1]) {
            int j = KTOK - 1;
            while (j > 0 && top[j - 1] > e) { top[j] = top[j - 1]; j--; }
            top[j] = e;
        }
    }
    for (int p = 0; p < KTOK; p++) sel[node * KTOK + p] = (p < m) ? top[p] : -1;
}

// ---------------------------------------------------------------- weight fragment prep
// B-frag (16x16x32): lane l elem i holds B[kt*32+(l>>4)*8+i][nt*16+(l&15)]
// wf: headWf[8][7][64][8]@0 ; wg1f(=ch1_w*ln_c_g)[4][25][64][8]@28672 ;
//     w2f[13][7][64][8]@79872 ; tok1f[64][8]@126464 ; tok2f[2][64][8]@126976
// extras (f32): Sg1[400] = sum_k ch1_w*g ; b1p[400] = sum_k ch1_w*b + ch1_b
__global__ void prep_kernel(const float* __restrict__ head_w, const float* __restrict__ ch1_w,
                            const float* __restrict__ ch2_w, const float* __restrict__ tok1_w,
                            const float* __restrict__ tok2_w,
                            const float* __restrict__ ln_c_g, const float* __restrict__ ln_c_b,
                            const float* __restrict__ ch1_b,
                            unsigned short* __restrict__ wf,
                            float* __restrict__ Sg1, float* __restrict__ b1p) {
    int i = blockIdx.x * blockDim.x + threadIdx.x;
    if (i >= 128000) {
        int h = i - 128000;
        if (h < 400) {
            float sg = 0.f, sb = 0.f;
            for (int k = 0; k < 100; k++) {
                float w = ch1_w[h * 100 + k];
                sg += w * ln_c_g[k];
                sb += w * ln_c_b[k];
            }
            Sg1[h] = sg;
            b1p[h] = sb + ch1_b[h];
        }
        return;
    }
    float val = 0.0f;
    if (i < 28672) {
        int ii = i & 7, lane = (i >> 3) & 63, rest = i >> 9;
        int nt = rest % 7, kt = rest / 7;
        int k = kt * 32 + ((lane >> 4) << 3) + ii;
        int n = nt * 16 + (lane & 15);
        if (k < 200 && n < 100) val = head_w[n * 200 + k];
    } else if (i < 79872) {
        int j = i - 28672;
        int ii = j & 7, lane = (j >> 3) & 63, rest = j >> 9;
        int nt = rest % 25, kt = rest / 25;
        int k = kt * 32 + ((lane >> 4) << 3) + ii;
        int n = nt * 16 + (lane & 15);
        if (k < 100) val = ch1_w[n * 100 + k] * ln_c_g[k];
    } else if (i < 126464) {
        int j = i - 79872;
        int ii = j & 7, lane = (j >> 3) & 63, rest = j >> 9;
        int nt = rest % 7, kt = rest / 7;
        int k = kt * 32 + ((lane >> 4) << 3) + ii;
        int n = nt * 16 + (lane & 15);
        if (k < 400 && n < 100) val = ch2_w[n * 400 + k];
    } else if (i < 126976) {
        int j = i - 126464;
        int ii = j & 7, lane = (j >> 3) & 63;
        int k = ((lane >> 4) << 3) + ii;
        int n = lane & 15;
        if (k < 30 && n < 15) val = tok1_w[n * 30 + k];
    } else {
        int j = i - 126976;
        int ii = j & 7, lane = (j >> 3) & 63, nt = j >> 9;
        int k = ((lane >> 4) << 3) + ii;
        int n = nt * 16 + (lane & 15);
        if (k < 15 && n < 30) val = tok2_w[n * 15 + k];
    }
    wf[i] = f2bf(val);
}

// ---------------------------------------------------------------- fused per-node forward
// 2 nodes/block, 1 wave/node, zero __syncthreads. LDS/block ~18.4KB.
// waves_per_eu=3 (VGPR budget 168) -- (128,4) spilled catastrophically in r8
// (WRITE_SIZE 920MB of scratch); this structure needs >128 VGPR live in Phase A/C.
__global__ __launch_bounds__(128, 3) void fused_node_kernel(
    const float* __restrict__ edge_attr, const float* __restrict__ edge_time,
    const int* __restrict__ sel, const unsigned short* __restrict__ wf,
    const float* __restrict__ head_b,
    const float* __restrict__ ln_t_g, const float* __restrict__ ln_t_b,
    const float* __restrict__ tok1_b, const float* __restrict__ tok2_b,
    const float* __restrict__ Sg1, const float* __restrict__ b1p,
    const float* __restrict__ ch2_b,
    const float* __restrict__ ln_h_g, const float* __restrict__ ln_h_b,
    const float* __restrict__ out_w, const float* __restrict__ out_b,
    float* __restrict__ out, int N) {

    __shared__ __align__(16) unsigned short xb2[2][32 * 104];  // x -> h_token (6656 B/wave)
    __shared__ __align__(16) unsigned short scr2[2][1280];     // av-batches / y / cbw / stF (2560 B/wave)

    const int t = threadIdx.x;
    const int wv = t >> 6, l = t & 63;
    const int g = l >> 4, c16 = l & 15;
    unsigned short* xbw = xb2[wv];
    unsigned short* scrw = scr2[wv];
    char* scrb = (char*)scrw;
    const int node = blockIdx.x * 2 + wv;

    const s16x8 zfrag = {0, 0, 0, 0, 0, 0, 0, 0};
    const f32x4 zacc = {0.f, 0.f, 0.f, 0.f};

    const s16x8* headWf_v = (const s16x8*)(wf);
    const s16x8* wg1f_v   = (const s16x8*)(wf + 28672);
    const s16x8* w2f_v    = (const s16x8*)(wf + 79872);
    const s16x8* tok1f_v  = (const s16x8*)(wf + 126464);
    const s16x8* tok2f_v  = (const s16x8*)(wf + 126976);

    // ---- per-lane edge info (no LDS)
    int eload = (l < KTOK && node < N) ? sel[node * KTOK + l] : -1;
    unsigned long long vmask = __ballot(eload >= 0);   // bit r = validity of token row r
    int e0 = __shfl(eload, c16);
    int e1 = __shfl(eload, 16 + c16);
    float tt0 = (e0 >= 0) ? edge_time[e0] : 0.f;
    float tt1 = (e1 >= 0) ? edge_time[e1] : 0.f;
    const float INV2PI = 0.15915494309189535f;
    float Trev0 = tt0 * INV2PI, Trev1 = tt1 * INV2PI;
    const float* ab0 = edge_attr + (size_t)(e0 < 0 ? 0 : e0) * 100;
    const float* ab1 = edge_attr + (size_t)(e1 < 0 ? 0 : e1) * 100;

    // ================= Phase A: head GEMM, A-frags built in registers =================
    f32x4 hacc[2][7];
    #pragma unroll
    for (int a = 0; a < 2; a++)
        #pragma unroll
        for (int c = 0; c < 7; c++) hacc[a][c] = zacc;

    #pragma unroll
    for (int kc = 0; kc < 4; kc++) {
        s16x8 af[2][2];
        #pragma unroll
        for (int mt = 0; mt < 2; mt++) {
            const float Trev = mt ? Trev1 : Trev0;
            const float* abm = mt ? ab1 : ab0;
            #pragma unroll
            for (int kk = 0; kk < 2; kk++) {
                const int kb0 = kc * 64 + kk * 32;   // compile-time
                union { s16x8 v; unsigned u[4]; } r;
                if (kb0 + 32 <= 100) {
                    // pure temporal: IN[k] = cos(t * rho^k), rho^k in revolutions
                    float Ab = Trev * exp2_fast(-CEXP * (float)(kb0 + g * 8));
                    #pragma unroll
                    for (int i2 = 0; i2 < 8; i2 += 2) {
                        float v0 = cos_rev(Ab * exp2f(-CEXP * (float)i2));
                        float v1 = cos_rev(Ab * exp2f(-CEXP * (float)(i2 + 1)));
                        r.u[i2 >> 1] = cvt_pk_bf16(v0, v1);
                    }
                } else if (kb0 == 96) {
                    // mixed: g0 has k 96..103 (4 cos + 4 attr), g>=1 all attr
                    int aoff = kb0 + g * 8 - 100;
                    int ac = aoff < 0 ? 0 : aoff;           // multiples of 4 -> aligned
                    const float* ap = abm + ac;
                    float4 A0 = *(const float4*)ap;
                    float4 A1 = *(const float4*)(ap + 4);
                    float fa[8] = {A0.x, A0.y, A0.z, A0.w, A1.x, A1.y, A1.z, A1.w};
                    float Ab = Trev * exp2_fast(-CEXP * (float)(kb0 + g * 8));
                    #pragma unroll
                    for (int i2 = 0; i2 < 8; i2 += 2) {
                        float cc0 = cos_rev(Ab * exp2f(-CEXP * (float)i2));
                        float cc1 = cos_rev(Ab * exp2f(-CEXP * (float)(i2 + 1)));
                        float a0 = (g == 0) ? ((i2 >= 4) ? fa[(i2 >= 4) ? i2 - 4 : 0] : 0.f) : fa[i2];
                        float a1 = (g == 0) ? ((i2 + 1 >= 4) ? fa[(i2 + 1 >= 4) ? i2 - 3 : 0] : 0.f) : fa[i2 + 1];
                        int k0 = kb0 + g * 8 + i2;
                        float v0 = (k0 < 100) ? cc0 : a0;
                        float v1 = (k0 + 1 < 100) ? cc1 : a1;
                        r.u[i2 >> 1] = cvt_pk_bf16(v0, v1);
                    }
                } else if (kb0 <= 160) {
                    // pure attr
                    int ac = kb0 + g * 8 - 100;
                    const float* ap = abm + ac;
                    float4 A0 = *(const float4*)ap;
                    float4 A1 = *(const float4*)(ap + 4);
                    r.u[0] = cvt_pk_bf16(A0.x, A0.y);
                    r.u[1] = cvt_pk_bf16(A0.z, A0.w);
                    r.u[2] = cvt_pk_bf16(A1.x, A1.y);
                    r.u[3] = cvt_pk_bf16(A1.z, A1.w);
                } else if (kb0 == 192) {
                    // attr tail + zeros (k>=200)
                    int aoff = kb0 + g * 8 - 100;
                    int ac = aoff > 92 ? 92 : aoff;
                    const float* ap = abm + ac;
                    float4 A0 = *(const float4*)ap;
                    float4 A1 = *(const float4*)(ap + 4);
                    float fa[8] = {A0.x, A0.y, A0.z, A0.w, A1.x, A1.y, A1.z, A1.w};
                    #pragma unroll
                    for (int i2 = 0; i2 < 8; i2 += 2) {
                        int k0 = kb0 + g * 8 + i2;
                        float v0 = (k0 < 200) ? fa[i2] : 0.f;
                        float v1 = (k0 + 1 < 200) ? fa[i2 + 1] : 0.f;
                        r.u[i2 >> 1] = cvt_pk_bf16(v0, v1);
                    }
                } else {
                    r.u[0] = 0; r.u[1] = 0; r.u[2] = 0; r.u[3] = 0;
                }
                af[mt][kk] = r.v;
            }
        }
        #pragma unroll
        for (int nt = 0; nt < 7; nt++) {
            #pragma unroll
            for (int kk = 0; kk < 2; kk++) {
                s16x8 bf = headWf_v[((kc * 2 + kk) * 7 + nt) * 64 + l];
                #pragma unroll
                for (int mt = 0; mt < 2; mt++)
                    hacc[mt][nt] = __builtin_amdgcn_mfma_f32_16x16x32_bf16(af[mt][kk], bf, hacc[mt][nt], 0, 0, 0);
            }
        }
    }

    // ---- per-lane coefficient caches (loaded AFTER Phase A to keep its reg peak low)
    float g7[7], b7[7], hb7[7];
    #pragma unroll
    for (int nt = 0; nt < 7; nt++) {
        int cc = nt * 16 + c16; if (cc > 99) cc = 99;
        g7[nt] = ln_t_g[cc]; b7[nt] = ln_t_b[cc]; hb7[nt] = head_b[cc];
    }

    // ---- x = mask(hacc + bias); rows with sel<0 and cols>=100 are exact 0
    #pragma unroll
    for (int mt = 0; mt < 2; mt++)
        #pragma unroll
        for (int nt = 0; nt < 7; nt++)
            #pragma unroll
            for (int jj = 0; jj < 4; jj++) {
                int row = mt * 16 + g * 4 + jj;
                bool ok = (((vmask >> row) & 1ull) != 0) && (nt < 6 || c16 < 4);
                hacc[mt][nt][jj] = ok ? (hacc[mt][nt][jj] + hb7[nt]) : 0.f;
            }

    // ---- x-store to xbw [32][104] (+ zero pad cols 100..103)
    #pragma unroll
    for (int mt = 0; mt < 2; mt++)
        #pragma unroll
        for (int nt = 0; nt < 7; nt++)
            #pragma unroll
            for (int jj = 0; jj < 4; jj++) {
                int row = mt * 16 + g * 4 + jj;
                int col = nt * 16 + c16;
                if (col < 100)      xbw[row * 104 + col] = cvt_bf16(hacc[mt][nt][jj]);
                else if (col < 104) xbw[row * 104 + col] = 0;
            }

    // ---- LN_t stats per row (reduce over 16 col-lanes)
    float mv[2][4], rv[2][4];
    #pragma unroll
    for (int mt = 0; mt < 2; mt++)
        #pragma unroll
        for (int jj = 0; jj < 4; jj++) {
            float s = 0.f, s2 = 0.f;
            #pragma unroll
            for (int nt = 0; nt < 7; nt++) {
                float v = hacc[mt][nt][jj];
                s += v;
                s2 = fmaf(v, v, s2);
            }
            #pragma unroll
            for (int msk = 1; msk < 16; msk <<= 1) {
                s  += __shfl_xor(s, msk);
                s2 += __shfl_xor(s2, msk);
            }
            float m = s * 0.01f;
            float var = fmaxf(s2 * 0.01f - m * m, 0.f);
            mv[mt][jj] = m;
            rv[mt][jj] = rsqrtf(var + 1e-5f);
        }

    // ---- scatter normalized LN_t into A-slot layout (2-nt batches), read av A-frags
    s16x8 av[7];
    #pragma unroll
    for (int nb = 0; nb < 4; nb++) {
        #pragma unroll
        for (int nn = 0; nn < 2; nn++) {
            int nt = nb * 2 + nn;
            if (nt < 7) {
                #pragma unroll
                for (int mt = 0; mt < 2; mt++) {
                    float h0 = fmaf((hacc[mt][nt][0] - mv[mt][0]) * rv[mt][0], g7[nt], b7[nt]);
                    float h1 = fmaf((hacc[mt][nt][1] - mv[mt][1]) * rv[mt][1], g7[nt], b7[nt]);
                    float h2 = fmaf((hacc[mt][nt][2] - mv[mt][2]) * rv[mt][2], g7[nt], b7[nt]);
                    float h3 = fmaf((hacc[mt][nt][3] - mv[mt][3]) * rv[mt][3], g7[nt], b7[nt]);
                    unsigned w0 = cvt_pk_bf16(h0, h1);
                    unsigned w1 = cvt_pk_bf16(h2, h3);
                    int ba = (nt & 1) * 1024 + (c16 + 32 * mt + 16 * (g >> 1)) * 16 + 8 * (g & 1);
                    *(uint2*)(scrb + ba) = make_uint2(w0, w1);
                }
            }
        }
        SB();
        #pragma unroll
        for (int nn = 0; nn < 2; nn++) {
            int nt = nb * 2 + nn;
            if (nt < 7)
                av[nt] = *(const s16x8*)(scrb + (nt & 1) * 1024 + l * 16);
        }
        SB();
    }

    // ================= Phase B: token mixer (per ch-tile; y via slot buffer) =================
    {
        s16x8 b1 = tok1f_v[l];
        float bias1 = (c16 < 15) ? tok1_b[c16] : 0.f;
        s16x8 b2a = tok2f_v[l];
        s16x8 b2b = tok2f_v[64 + l];
        float tb0 = tok2_b[c16];
        float tb1 = (c16 < 14) ? tok2_b[16 + c16] : 0.f;
        #pragma unroll
        for (int mt7 = 0; mt7 < 7; mt7++) {
            f32x4 y = __builtin_amdgcn_mfma_f32_16x16x32_bf16(av[mt7], b1, zacc, 0, 0, 0);
            #pragma unroll
            for (int jj = 0; jj < 4; jj++) {
                int ba = ((g * 4 + jj) + (c16 >> 3) * 16) * 16 + (c16 & 7) * 2;
                *(unsigned short*)(scrb + ba) = cvt_bf16(gelu(y[jj] + bias1));
            }
            SB();
            s16x8 a2 = zfrag;
            if (g < 2) a2 = *(const s16x8*)(scrb + l * 16);
            SB();
            f32x4 d0 = __builtin_amdgcn_mfma_f32_16x16x32_bf16(a2, b2a, zacc, 0, 0, 0);
            f32x4 d1 = __builtin_amdgcn_mfma_f32_16x16x32_bf16(a2, b2b, zacc, 0, 0, 0);
            #pragma unroll
            for (int jj = 0; jj < 4; jj++) {
                int chD = mt7 * 16 + g * 4 + jj;
                if (chD < 100) {
                    int idx0 = c16 * 104 + chD;
                    xbw[idx0] = cvt_bf16(bf2f(xbw[idx0]) + d0[jj] + tb0);
                    int tok1i = 16 + c16;
                    if (tok1i < 30) {
                        int idx1 = tok1i * 104 + chD;
                        xbw[idx1] = cvt_bf16(bf2f(xbw[idx1]) + d1[jj] + tb1);
                    }
                }
            }
            SB();
        }
    }

    // ================= Phase C: ch1 (LN_c folded) -> gelu -> ch2 =================
    unsigned short* cbw = scrw;   // [32][40] u16 ping buffer
    f32x4 acc2[2][7];
    {
        s16x8 a1f[2][4];
        #pragma unroll
        for (int mt = 0; mt < 2; mt++)
            #pragma unroll
            for (int kk = 0; kk < 4; kk++) {
                s16x8 a = zfrag;
                if (kk < 3 || g == 0)
                    a = *(const s16x8*)&xbw[(mt * 16 + c16) * 104 + kk * 32 + g * 8];
                a1f[mt][kk] = a;
            }
        SB();

        // LN_c stats from raw h_token (a1f regs): per tok = c16 (within mt tile)
        float rs_r[2][4], rm_r[2][4];
        {
            float mA[2], rA[2];
            #pragma unroll
            for (int mt = 0; mt < 2; mt++) {
                float s = 0.f, s2 = 0.f;
                #pragma unroll
                for (int kk = 0; kk < 4; kk++)
                    #pragma unroll
                    for (int i = 0; i < 8; i++) {
                        float f = bf2f((unsigned short)a1f[mt][kk][i]);
                        s += f;
                        s2 = fmaf(f, f, s2);
                    }
                s  += __shfl_xor(s, 16);  s  += __shfl_xor(s, 32);
                s2 += __shfl_xor(s2, 16); s2 += __shfl_xor(s2, 32);
                float m = s * 0.01f;
                float var = fmaxf(s2 * 0.01f - m * m, 0.f);
                mA[mt] = m;
                rA[mt] = rsqrtf(var + 1e-5f);
            }
            #pragma unroll
            for (int mt = 0; mt < 2; mt++)
                #pragma unroll
                for (int jj = 0; jj < 4; jj++) {
                    int src = g * 4 + jj;
                    float mm = __shfl(mA[mt], src);
                    float rr = __shfl(rA[mt], src);
                    rs_r[mt][jj] = rr;
                    rm_r[mt][jj] = rr * mm;
                }
        }

        #pragma unroll
        for (int a = 0; a < 2; a++)
            #pragma unroll
            for (int c = 0; c < 7; c++) acc2[a][c] = zacc;

        for (int hc = 0; hc < 13; hc++) {
            f32x4 acc1[2][2];
            float Sg[2], Bp[2];
            #pragma unroll
            for (int a = 0; a < 2; a++) { acc1[a][0] = zacc; acc1[a][1] = zacc; }
            #pragma unroll
            for (int ntl = 0; ntl < 2; ntl++) {
                int ntg = hc * 2 + ntl;
                if (ntg < 25) {
                    int h = ntg * 16 + c16;
                    Sg[ntl] = Sg1[h];
                    Bp[ntl] = b1p[h];
                    #pragma unroll
                    for (int kk = 0; kk < 4; kk++) {
                        s16x8 bfr = wg1f_v[(kk * 25 + ntg) * 64 + l];
                        #pragma unroll
                        for (int mt = 0; mt < 2; mt++)
                            acc1[mt][ntl] = __builtin_amdgcn_mfma_f32_16x16x32_bf16(a1f[mt][kk], bfr, acc1[mt][ntl], 0, 0, 0);
                    }
                }
            }
            #pragma unroll
            for (int ntl = 0; ntl < 2; ntl++) {
                int ntg = hc * 2 + ntl;
                if (ntg < 25) {
                    #pragma unroll
                    for (int mt = 0; mt < 2; mt++)
                        #pragma unroll
                        for (int jj = 0; jj < 4; jj++) {
                            int row = mt * 16 + g * 4 + jj;
                            float h1 = fmaf(rs_r[mt][jj], acc1[mt][ntl][jj],
                                            fmaf(-rm_r[mt][jj], Sg[ntl], Bp[ntl]));
                            cbw[row * 40 + ntl * 16 + c16] = cvt_bf16(gelu(h1));
                        }
                }
            }
            SB();
            s16x8 a2f[2];
            #pragma unroll
            for (int mt = 0; mt < 2; mt++)
                a2f[mt] = *(const s16x8*)&cbw[(mt * 16 + c16) * 40 + g * 8];
            SB();
            #pragma unroll
            for (int nt2 = 0; nt2 < 7; nt2++) {
                s16x8 b2f = w2f_v[(hc * 7 + nt2) * 64 + l];
                #pragma unroll
                for (int mt = 0; mt < 2; mt++)
                    acc2[mt][nt2] = __builtin_amdgcn_mfma_f32_16x16x32_bf16(a2f[mt], b2f, acc2[mt][nt2], 0, 0, 0);
            }
            SB();
        }
    }

    // ================= Phase D: h_channel -> LN_h -> mean -> out proj (registers) =================
    #pragma unroll
    for (int nt = 0; nt < 7; nt++) {
        int col = nt * 16 + c16;
        if (col < 100) {
            float bias = ch2_b[col];
            #pragma unroll
            for (int mt = 0; mt < 2; mt++)
                #pragma unroll
                for (int jj = 0; jj < 4; jj++) {
                    int row = mt * 16 + g * 4 + jj;
                    acc2[mt][nt][jj] += bias + bf2f(xbw[row * 104 + col]);
                }
        }
    }
    float m_[2][4], rs_[2][4];
    #pragma unroll
    for (int mt = 0; mt < 2; mt++)
        #pragma unroll
        for (int jj = 0; jj < 4; jj++) {
            float s = 0.f, s2 = 0.f;
            #pragma unroll
            for (int nt = 0; nt < 7; nt++) {
                float v = acc2[mt][nt][jj];
                s += v;
                s2 = fmaf(v, v, s2);
            }
            #pragma unroll
            for (int msk = 1; msk < 16; msk <<= 1) {
                s  += __shfl_xor(s, msk);
                s2 += __shfl_xor(s2, msk);
            }
            float m = s * 0.01f;
            float var = fmaxf(s2 * 0.01f - m * m, 0.f);
            m_[mt][jj]  = m;
            rs_[mt][jj] = rsqrtf(var + 1e-5f);
        }
    float cs[7];
    #pragma unroll
    for (int nt = 0; nt < 7; nt++) cs[nt] = 0.f;
    #pragma unroll
    for (int mt = 0; mt < 2; mt++)
        #pragma unroll
        for (int jj = 0; jj < 4; jj++) {
            int row = mt * 16 + g * 4 + jj;
            if (row < 30) {
                float m = m_[mt][jj], rs = rs_[mt][jj];
                #pragma unroll
                for (int nt = 0; nt < 7; nt++)
                    cs[nt] = fmaf(acc2[mt][nt][jj] - m, rs, cs[nt]);
            }
        }
    #pragma unroll
    for (int nt = 0; nt < 7; nt++) {
        cs[nt] += __shfl_xor(cs[nt], 16);
        cs[nt] += __shfl_xor(cs[nt], 32);
    }
    float* stF = (float*)scrw;     // cbw dead
    if (g == 0) {
        #pragma unroll
        for (int nt = 0; nt < 7; nt++) {
            int col = nt * 16 + c16;
            if (col < 100)
                stF[col] = ln_h_g[col] * cs[nt] * (1.0f / 30.0f) + ln_h_b[col];
        }
    }
    SB();
    #pragma unroll
    for (int p = 0; p < 2; p++) {
        int o = p * 64 + l;
        if (o < 100 && node < N) {
            float a = out_b[o];
            const float* wr = out_w + o * 100;
            #pragma unroll
            for (int c = 0; c < 100; c += 4) {
                float4 w4 = *(const float4*)(wr + c);
                f32x4 t4 = *(const f32x4*)&stF[c];
                a += w4.x * t4[0] + w4.y * t4[1] + w4.z * t4[2] + w4.w * t4[3];
            }
            out[(size_t)node * 100 + o] = a;
        }
    }
}

// ---------------------------------------------------------------- launch

extern "C" void kernel_launch(void* const* d_in, const int* in_sizes, int n_in,
                              void* d_out, int out_size, void* d_ws, size_t ws_size,
                              hipStream_t stream) {
    const float* edge_attr  = (const float*)d_in[0];
    const float* edge_time  = (const float*)d_in[1];
    const int*   node_batch = (const int*)d_in[2];
    const float* head_w = (const float*)d_in[4];
    const float* head_b = (const float*)d_in[5];
    const float* ln_t_g = (const float*)d_in[6];
    const float* ln_t_b = (const float*)d_in[7];
    const float* tok1_w = (const float*)d_in[8];
    const float* tok1_b = (const float*)d_in[9];
    const float* tok2_w = (const float*)d_in[10];
    const float* tok2_b = (const float*)d_in[11];
    const float* ln_c_g = (const float*)d_in[12];
    const float* ln_c_b = (const float*)d_in[13];
    const float* ch1_w  = (const float*)d_in[14];
    const float* ch1_b  = (const float*)d_in[15];
    const float* ch2_w  = (const float*)d_in[16];
    const float* ch2_b  = (const float*)d_in[17];
    const float* ln_h_g = (const float*)d_in[18];
    const float* ln_h_b = (const float*)d_in[19];
    const float* out_w  = (const float*)d_in[20];
    const float* out_b  = (const float*)d_in[21];
    float* out = (float*)d_out;

    const int E = in_sizes[2];
    const int N = out_size / HIDC;

    int* cnt     = (int*)d_ws;                            // N
    int* cursor  = cnt + N;                               // N
    int* offsets = cursor + N;                            // N
    int* order   = offsets + N;                           // E
    int* sel     = order + E;                             // N*K
    unsigned short* wf = (unsigned short*)(sel + (size_t)N * KTOK);  // 128000 u16
    float* Sg1 = (float*)(wf + 128000);                   // 400
    float* b1p = Sg1 + 400;                               // 400
    int*   bsum = (int*)(b1p + 400);                      // <=64

    const int nbk = (N + 1023) / 1024;

    hipMemsetAsync(cnt, 0, (size_t)2 * N * sizeof(int), stream);
    count_kernel<<<(E + 255) / 256, 256, 0, stream>>>(node_batch, cnt, E);
    scanA_kernel<<<nbk, 1024, 0, stream>>>(cnt, offsets, bsum, N);
    scanB_kernel<<<1, 64, 0, stream>>>(bsum, nbk);
    scanC_kernel<<<(N + 255) / 256, 256, 0, stream>>>(offsets, bsum, N);
    fill_kernel<<<(E + 255) / 256, 256, 0, stream>>>(node_batch, cursor, offsets, order, E);
    select_kernel<<<(N + 255) / 256, 256, 0, stream>>>(cnt, offsets, order, sel, N);
    prep_kernel<<<502, 256, 0, stream>>>(head_w, ch1_w, ch2_w, tok1_w, tok2_w,
                                         ln_c_g, ln_c_b, ch1_b, wf, Sg1, b1p);
    fused_node_kernel<<<(N + 1) / 2, 128, 0, stream>>>(
        edge_attr, edge_time, sel, wf, head_b,
        ln_t_g, ln_t_b, tok1_b, tok2_b, Sg1, b1p,
        ch2_b, ln_h_g, ln_h_b, out_w, out_b, out, N);
}

// Round 10
// 1064.074 us; speedup vs baseline: 1.6083x; 1.0634x over previous
//
#include <hip/hip_runtime.h>
#include <math.h>

#define KTOK 30
#define HIDC 100
#define SB() __builtin_amdgcn_sched_barrier(0)
#define CEXP 0.33554829241286486f

typedef short s16x8 __attribute__((ext_vector_type(8)));
typedef float f32x4 __attribute__((ext_vector_type(4)));

// ---------------------------------------------------------------- helpers
__device__ __forceinline__ unsigned cvt_pk_bf16(float lo, float hi) {
    unsigned r;
    asm("v_cvt_pk_bf16_f32 %0, %1, %2" : "=v"(r) : "v"(lo), "v"(hi));
    return r;
}
__device__ __forceinline__ unsigned short cvt_bf16(float x) {
    unsigned r;
    asm("v_cvt_pk_bf16_f32 %0, %1, 0" : "=v"(r) : "v"(x));
    return (unsigned short)r;
}
__device__ __forceinline__ float bf2f(unsigned short h) {
    return __uint_as_float(((unsigned)h) << 16);
}
__device__ __forceinline__ float exp2_fast(float x) {
    float r;
    asm("v_exp_f32 %0, %1" : "=v"(r) : "v"(x));
    return r;
}
__device__ __forceinline__ float cos_rev(float rev) {   // input in revolutions, |rev|<1
    float r;
    asm("v_cos_f32 %0, %1" : "=v"(r) : "v"(rev));
    return r;
}
__device__ __forceinline__ unsigned short f2bf(float f) {
    unsigned u = __float_as_uint(f);
    unsigned r = (u + 0x7FFFu + ((u >> 16) & 1u)) >> 16;
    return (unsigned short)r;
}
// tanh-form GELU, log2e folded: x / (1 + 2^(-x*(c1+c2*x^2)))
__device__ __forceinline__ float gelu(float x) {
    float s = x * x;
    float t = fmaf(s, 0.10294334f, 2.3022082f);
    float e = exp2_fast(-x * t);
    return x * __builtin_amdgcn_rcpf(1.0f + e);
}

// ---------------------------------------------------------------- selection pipeline
__global__ void count_kernel(const int* __restrict__ nb, int* __restrict__ cnt, int E) {
    int e = blockIdx.x * blockDim.x + threadIdx.x;
    if (e < E) atomicAdd(&cnt[nb[e]], 1);
}

__global__ void scanA_kernel(const int* __restrict__ cnt, int* __restrict__ offsets,
                             int* __restrict__ bsum, int n) {
    __shared__ int sd[1024];
    int tid = threadIdx.x;
    int i = blockIdx.x * 1024 + tid;
    int v = (i < n) ? cnt[i] : 0;
    sd[tid] = v;
    __syncthreads();
    for (int off = 1; off < 1024; off <<= 1) {
        int tv = (tid >= off) ? sd[tid - off] : 0;
        __syncthreads();
        sd[tid] += tv;
        __syncthreads();
    }
    if (i < n) offsets[i] = sd[tid] - v;            // block-local exclusive
    if (tid == 1023) bsum[blockIdx.x] = sd[1023];   // block total
}

__global__ void scanB_kernel(int* __restrict__ bsum, int nbk) {
    if (threadIdx.x == 0 && blockIdx.x == 0) {
        int run = 0;
        for (int b = 0; b < nbk; b++) { int tv = bsum[b]; bsum[b] = run; run += tv; }
    }
}

__global__ void scanC_kernel(int* __restrict__ offsets, const int* __restrict__ bsum, int n) {
    int i = blockIdx.x * blockDim.x + threadIdx.x;
    if (i < n) offsets[i] += bsum[i >> 10];
}

__global__ void fill_kernel(const int* __restrict__ nb, int* __restrict__ cursor,
                            const int* __restrict__ offsets, int* __restrict__ order, int E) {
    int e = blockIdx.x * blockDim.x + threadIdx.x;
    if (e >= E) return;
    int n = nb[e];
    int p = atomicAdd(&cursor[n], 1);
    order[offsets[n] + p] = e;
}

__global__ void select_kernel(const int* __restrict__ cnt, const int* __restrict__ offsets,
                              const int* __restrict__ order, int* __restrict__ sel, int N) {
    int node = blockIdx.x * blockDim.x + threadIdx.x;
    if (node >= N) return;
    int c = cnt[node];
    int off = offsets[node];
    int top[KTOK];
    int m = 0;
    for (int i = 0; i < c; i++) {
        int e = order[off + i];
        if (m < KTOK) {
            int j = m++;
            while (j > 0 && top[j - 1] > e) { top[j] = top[j - 1]; j--; }
            top[j] = e;
        } else if (e < top[KTOK - 1]) {
            int j = KTOK - 1;
            while (j > 0 && top[j - 1] > e) { top[j] = top[j - 1]; j--; }
            top[j] = e;
        }
    }
    for (int p = 0; p < KTOK; p++) sel[node * KTOK + p] = (p < m) ? top[p] : -1;
}

// ---------------------------------------------------------------- weight fragment prep
// B-frag (16x16x32): lane l elem i holds B[kt*32+(l>>4)*8+i][nt*16+(l&15)]
// wf: headWf[8][7][64][8]@0 ; wg1f(=ch1_w*ln_c_g)[4][25][64][8]@28672 ;
//     w2f[13][7][64][8]@79872 ; tok1f[64][8]@126464 ; tok2f[2][64][8]@126976
// extras (f32): Sg1[400] = sum_k ch1_w*g ; b1p[400] = sum_k ch1_w*b + ch1_b
__global__ void prep_kernel(const float* __restrict__ head_w, const float* __restrict__ ch1_w,
                            const float* __restrict__ ch2_w, const float* __restrict__ tok1_w,
                            const float* __restrict__ tok2_w,
                            const float* __restrict__ ln_c_g, const float* __restrict__ ln_c_b,
                            const float* __restrict__ ch1_b,
                            unsigned short* __restrict__ wf,
                            float* __restrict__ Sg1, float* __restrict__ b1p) {
    int i = blockIdx.x * blockDim.x + threadIdx.x;
    if (i >= 128000) {
        int h = i - 128000;
        if (h < 400) {
            float sg = 0.f, sb = 0.f;
            for (int k = 0; k < 100; k++) {
                float w = ch1_w[h * 100 + k];
                sg += w * ln_c_g[k];
                sb += w * ln_c_b[k];
            }
            Sg1[h] = sg;
            b1p[h] = sb + ch1_b[h];
        }
        return;
    }
    float val = 0.0f;
    if (i < 28672) {
        int ii = i & 7, lane = (i >> 3) & 63, rest = i >> 9;
        int nt = rest % 7, kt = rest / 7;
        int k = kt * 32 + ((lane >> 4) << 3) + ii;
        int n = nt * 16 + (lane & 15);
        if (k < 200 && n < 100) val = head_w[n * 200 + k];
    } else if (i < 79872) {
        int j = i - 28672;
        int ii = j & 7, lane = (j >> 3) & 63, rest = j >> 9;
        int nt = rest % 25, kt = rest / 25;
        int k = kt * 32 + ((lane >> 4) << 3) + ii;
        int n = nt * 16 + (lane & 15);
        if (k < 100) val = ch1_w[n * 100 + k] * ln_c_g[k];
    } else if (i < 126464) {
        int j = i - 79872;
        int ii = j & 7, lane = (j >> 3) & 63, rest = j >> 9;
        int nt = rest % 7, kt = rest / 7;
        int k = kt * 32 + ((lane >> 4) << 3) + ii;
        int n = nt * 16 + (lane & 15);
        if (k < 400 && n < 100) val = ch2_w[n * 400 + k];
    } else if (i < 126976) {
        int j = i - 126464;
        int ii = j & 7, lane = (j >> 3) & 63;
        int k = ((lane >> 4) << 3) + ii;
        int n = lane & 15;
        if (k < 30 && n < 15) val = tok1_w[n * 30 + k];
    } else {
        int j = i - 126976;
        int ii = j & 7, lane = (j >> 3) & 63, nt = j >> 9;
        int k = ((lane >> 4) << 3) + ii;
        int n = nt * 16 + (lane & 15);
        if (k < 15 && n < 30) val = tok2_w[n * 15 + k];
    }
    wf[i] = f2bf(val);
}

// ---------------------------------------------------------------- fused per-node forward
// 2 nodes/block, 1 wave/node, zero __syncthreads. LDS/block ~23.5KB (regs cap waves
// at ~11/CU so LDS up to ~27KB is free). waves_per_eu=3 (VGPR budget 168; (128,4)
// spilled catastrophically in r8 -- do not lower).
__global__ __launch_bounds__(128, 3) void fused_node_kernel(
    const float* __restrict__ edge_attr, const float* __restrict__ edge_time,
    const int* __restrict__ sel, const unsigned short* __restrict__ wf,
    const float* __restrict__ head_b,
    const float* __restrict__ ln_t_g, const float* __restrict__ ln_t_b,
    const float* __restrict__ tok1_b, const float* __restrict__ tok2_b,
    const float* __restrict__ Sg1, const float* __restrict__ b1p,
    const float* __restrict__ ch2_b,
    const float* __restrict__ ln_h_g, const float* __restrict__ ln_h_b,
    const float* __restrict__ out_w, const float* __restrict__ out_b,
    float* __restrict__ out, int N) {

    __shared__ __align__(16) unsigned short xb2[2][32 * 104];  // x -> h_token (6656 B/wave)
    __shared__ __align__(16) unsigned short scr2[2][2560];     // scatter(4KB)/y(3.5KB)/cbw-dbuf(5KB)/stF (5120 B/wave)

    const int t = threadIdx.x;
    const int wv = t >> 6, l = t & 63;
    const int g = l >> 4, c16 = l & 15;
    unsigned short* xbw = xb2[wv];
    unsigned short* scrw = scr2[wv];
    char* scrb = (char*)scrw;
    const int node = blockIdx.x * 2 + wv;

    const s16x8 zfrag = {0, 0, 0, 0, 0, 0, 0, 0};
    const f32x4 zacc = {0.f, 0.f, 0.f, 0.f};

    const s16x8* headWf_v = (const s16x8*)(wf);
    const s16x8* wg1f_v   = (const s16x8*)(wf + 28672);
    const s16x8* w2f_v    = (const s16x8*)(wf + 79872);
    const s16x8* tok1f_v  = (const s16x8*)(wf + 126464);
    const s16x8* tok2f_v  = (const s16x8*)(wf + 126976);

    // ---- per-lane edge info (no LDS)
    int eload = (l < KTOK && node < N) ? sel[node * KTOK + l] : -1;
    unsigned long long vmask = __ballot(eload >= 0);   // bit r = validity of token row r
    int e0 = __shfl(eload, c16);
    int e1 = __shfl(eload, 16 + c16);
    float tt0 = (e0 >= 0) ? edge_time[e0] : 0.f;
    float tt1 = (e1 >= 0) ? edge_time[e1] : 0.f;
    const float INV2PI = 0.15915494309189535f;
    float Trev0 = tt0 * INV2PI, Trev1 = tt1 * INV2PI;
    const float* ab0 = edge_attr + (size_t)(e0 < 0 ? 0 : e0) * 100;
    const float* ab1 = edge_attr + (size_t)(e1 < 0 ? 0 : e1) * 100;

    // ================= Phase A: head GEMM, A-frags built in registers =================
    f32x4 hacc[2][7];
    #pragma unroll
    for (int a = 0; a < 2; a++)
        #pragma unroll
        for (int c = 0; c < 7; c++) hacc[a][c] = zacc;

    #pragma unroll
    for (int kc = 0; kc < 4; kc++) {
        s16x8 af[2][2];
        #pragma unroll
        for (int mt = 0; mt < 2; mt++) {
            const float Trev = mt ? Trev1 : Trev0;
            const float* abm = mt ? ab1 : ab0;
            #pragma unroll
            for (int kk = 0; kk < 2; kk++) {
                const int kb0 = kc * 64 + kk * 32;   // compile-time
                if (kb0 >= 224) { af[mt][kk] = zfrag; continue; }   // k>=200 all-zero block
                union { s16x8 v; unsigned u[4]; } r;
                if (kb0 + 32 <= 100) {
                    // pure temporal: IN[k] = cos(t * rho^k), rho^k in revolutions
                    float Ab = Trev * exp2_fast(-CEXP * (float)(kb0 + g * 8));
                    #pragma unroll
                    for (int i2 = 0; i2 < 8; i2 += 2) {
                        float v0 = cos_rev(Ab * exp2f(-CEXP * (float)i2));
                        float v1 = cos_rev(Ab * exp2f(-CEXP * (float)(i2 + 1)));
                        r.u[i2 >> 1] = cvt_pk_bf16(v0, v1);
                    }
                } else if (kb0 == 96) {
                    // mixed: g0 has k 96..103 (4 cos + 4 attr), g>=1 all attr
                    int aoff = kb0 + g * 8 - 100;
                    int ac = aoff < 0 ? 0 : aoff;           // multiples of 4 -> aligned
                    const float* ap = abm + ac;
                    float4 A0 = *(const float4*)ap;
                    float4 A1 = *(const float4*)(ap + 4);
                    float fa[8] = {A0.x, A0.y, A0.z, A0.w, A1.x, A1.y, A1.z, A1.w};
                    float Ab = Trev * exp2_fast(-CEXP * (float)(kb0 + g * 8));
                    #pragma unroll
                    for (int i2 = 0; i2 < 8; i2 += 2) {
                        float cc0 = cos_rev(Ab * exp2f(-CEXP * (float)i2));
                        float cc1 = cos_rev(Ab * exp2f(-CEXP * (float)(i2 + 1)));
                        float a0 = (g == 0) ? ((i2 >= 4) ? fa[(i2 >= 4) ? i2 - 4 : 0] : 0.f) : fa[i2];
                        float a1 = (g == 0) ? ((i2 + 1 >= 4) ? fa[(i2 + 1 >= 4) ? i2 - 3 : 0] : 0.f) : fa[i2 + 1];
                        int k0 = kb0 + g * 8 + i2;
                        float v0 = (k0 < 100) ? cc0 : a0;
                        float v1 = (k0 + 1 < 100) ? cc1 : a1;
                        r.u[i2 >> 1] = cvt_pk_bf16(v0, v1);
                    }
                } else if (kb0 <= 160) {
                    // pure attr
                    int ac = kb0 + g * 8 - 100;
                    const float* ap = abm + ac;
                    float4 A0 = *(const float4*)ap;
                    float4 A1 = *(const float4*)(ap + 4);
                    r.u[0] = cvt_pk_bf16(A0.x, A0.y);
                    r.u[1] = cvt_pk_bf16(A0.z, A0.w);
                    r.u[2] = cvt_pk_bf16(A1.x, A1.y);
                    r.u[3] = cvt_pk_bf16(A1.z, A1.w);
                } else {
                    // kb0 == 192: attr tail + zeros (k>=200)
                    int aoff = kb0 + g * 8 - 100;
                    int ac = aoff > 92 ? 92 : aoff;
                    const float* ap = abm + ac;
                    float4 A0 = *(const float4*)ap;
                    float4 A1 = *(const float4*)(ap + 4);
                    float fa[8] = {A0.x, A0.y, A0.z, A0.w, A1.x, A1.y, A1.z, A1.w};
                    #pragma unroll
                    for (int i2 = 0; i2 < 8; i2 += 2) {
                        int k0 = kb0 + g * 8 + i2;
                        float v0 = (k0 < 200) ? fa[i2] : 0.f;
                        float v1 = (k0 + 1 < 200) ? fa[i2 + 1] : 0.f;
                        r.u[i2 >> 1] = cvt_pk_bf16(v0, v1);
                    }
                }
                af[mt][kk] = r.v;
            }
        }
        #pragma unroll
        for (int nt = 0; nt < 7; nt++) {
            #pragma unroll
            for (int kk = 0; kk < 2; kk++) {
                if (kc == 3 && kk == 1) continue;   // zero K-block: skip load + MFMA
                s16x8 bf = headWf_v[((kc * 2 + kk) * 7 + nt) * 64 + l];
                #pragma unroll
                for (int mt = 0; mt < 2; mt++)
                    hacc[mt][nt] = __builtin_amdgcn_mfma_f32_16x16x32_bf16(af[mt][kk], bf, hacc[mt][nt], 0, 0, 0);
            }
        }
    }

    // ---- per-lane coefficient caches (loaded AFTER Phase A to keep its reg peak low)
    float g7[7], b7[7], hb7[7];
    #pragma unroll
    for (int nt = 0; nt < 7; nt++) {
        int cc = nt * 16 + c16; if (cc > 99) cc = 99;
        g7[nt] = ln_t_g[cc]; b7[nt] = ln_t_b[cc]; hb7[nt] = head_b[cc];
    }

    // ---- x = mask(hacc + bias); rows with sel<0 and cols>=100 are exact 0
    #pragma unroll
    for (int mt = 0; mt < 2; mt++)
        #pragma unroll
        for (int nt = 0; nt < 7; nt++)
            #pragma unroll
            for (int jj = 0; jj < 4; jj++) {
                int row = mt * 16 + g * 4 + jj;
                bool ok = (((vmask >> row) & 1ull) != 0) && (nt < 6 || c16 < 4);
                hacc[mt][nt][jj] = ok ? (hacc[mt][nt][jj] + hb7[nt]) : 0.f;
            }

    // ---- x-store to xbw [32][104] (+ zero pad cols 100..103)
    #pragma unroll
    for (int mt = 0; mt < 2; mt++)
        #pragma unroll
        for (int nt = 0; nt < 7; nt++)
            #pragma unroll
            for (int jj = 0; jj < 4; jj++) {
                int row = mt * 16 + g * 4 + jj;
                int col = nt * 16 + c16;
                if (col < 100)      xbw[row * 104 + col] = cvt_bf16(hacc[mt][nt][jj]);
                else if (col < 104) xbw[row * 104 + col] = 0;
            }

    // ---- LN_t stats per row (reduce over 16 col-lanes)
    float mv[2][4], rv[2][4];
    #pragma unroll
    for (int mt = 0; mt < 2; mt++)
        #pragma unroll
        for (int jj = 0; jj < 4; jj++) {
            float s = 0.f, s2 = 0.f;
            #pragma unroll
            for (int nt = 0; nt < 7; nt++) {
                float v = hacc[mt][nt][jj];
                s += v;
                s2 = fmaf(v, v, s2);
            }
            #pragma unroll
            for (int msk = 1; msk < 16; msk <<= 1) {
                s  += __shfl_xor(s, msk);
                s2 += __shfl_xor(s2, msk);
            }
            float m = s * 0.01f;
            float var = fmaxf(s2 * 0.01f - m * m, 0.f);
            mv[mt][jj] = m;
            rv[mt][jj] = rsqrtf(var + 1e-5f);
        }

    // ---- scatter normalized LN_t into A-slot layout (2 batches: 4 + 3 nt), read av A-frags
    s16x8 av[7];
    #pragma unroll
    for (int nb = 0; nb < 2; nb++) {
        const int nt0 = nb ? 4 : 0;
        const int ntN = nb ? 3 : 4;
        #pragma unroll
        for (int nn = 0; nn < 4; nn++) {
            if (nn < ntN) {
                int nt = nt0 + nn;
                #pragma unroll
                for (int mt = 0; mt < 2; mt++) {
                    float h0 = fmaf((hacc[mt][nt][0] - mv[mt][0]) * rv[mt][0], g7[nt], b7[nt]);
                    float h1 = fmaf((hacc[mt][nt][1] - mv[mt][1]) * rv[mt][1], g7[nt], b7[nt]);
                    float h2 = fmaf((hacc[mt][nt][2] - mv[mt][2]) * rv[mt][2], g7[nt], b7[nt]);
                    float h3 = fmaf((hacc[mt][nt][3] - mv[mt][3]) * rv[mt][3], g7[nt], b7[nt]);
                    unsigned w0 = cvt_pk_bf16(h0, h1);
                    unsigned w1 = cvt_pk_bf16(h2, h3);
                    int ba = nn * 1024 + (c16 + 32 * mt + 16 * (g >> 1)) * 16 + 8 * (g & 1);
                    *(uint2*)(scrb + ba) = make_uint2(w0, w1);
                }
            }
        }
        SB();
        #pragma unroll
        for (int nn = 0; nn < 4; nn++) {
            if (nn < ntN)
                av[nt0 + nn] = *(const s16x8*)(scrb + nn * 1024 + l * 16);
        }
        SB();
    }

    // ================= Phase B: token mixer (batched; per-mt7 y regions) =================
    {
        s16x8 b1 = tok1f_v[l];
        float bias1 = (c16 < 15) ? tok1_b[c16] : 0.f;
        // all 7 tok1 MFMAs + gelu + y-writes first (independent chains)
        #pragma unroll
        for (int mt7 = 0; mt7 < 7; mt7++) {
            f32x4 y = __builtin_amdgcn_mfma_f32_16x16x32_bf16(av[mt7], b1, zacc, 0, 0, 0);
            #pragma unroll
            for (int jj = 0; jj < 4; jj++) {
                int ba = mt7 * 512 + (((g * 4 + jj) + (c16 >> 3) * 16) * 16 + (c16 & 7) * 2);
                *(unsigned short*)(scrb + ba) = cvt_bf16(gelu(y[jj] + bias1));
            }
        }
        SB();
        s16x8 b2a = tok2f_v[l];
        s16x8 b2b = tok2f_v[64 + l];
        float tb0 = tok2_b[c16];
        float tb1 = (c16 < 14) ? tok2_b[16 + c16] : 0.f;
        #pragma unroll
        for (int mt7 = 0; mt7 < 7; mt7++) {
            s16x8 a2 = zfrag;
            if (g < 2) a2 = *(const s16x8*)(scrb + mt7 * 512 + l * 16);
            f32x4 d0 = __builtin_amdgcn_mfma_f32_16x16x32_bf16(a2, b2a, zacc, 0, 0, 0);
            f32x4 d1 = __builtin_amdgcn_mfma_f32_16x16x32_bf16(a2, b2b, zacc, 0, 0, 0);
            #pragma unroll
            for (int jj = 0; jj < 4; jj++) {
                int chD = mt7 * 16 + g * 4 + jj;
                if (chD < 100) {
                    int idx0 = c16 * 104 + chD;
                    xbw[idx0] = cvt_bf16(bf2f(xbw[idx0]) + d0[jj] + tb0);
                    int tok1i = 16 + c16;
                    if (tok1i < 30) {
                        int idx1 = tok1i * 104 + chD;
                        xbw[idx1] = cvt_bf16(bf2f(xbw[idx1]) + d1[jj] + tb1);
                    }
                }
            }
        }
        SB();
    }

    // ================= Phase C: ch1 (LN_c folded) -> gelu -> ch2 (cbw double-buffered) =================
    unsigned short* cbw0 = scrw;          // [32][40] u16, 2560 B
    unsigned short* cbw1 = scrw + 1280;   // second buffer, 2560 B
    f32x4 acc2[2][7];
    {
        s16x8 a1f[2][4];
        #pragma unroll
        for (int mt = 0; mt < 2; mt++)
            #pragma unroll
            for (int kk = 0; kk < 4; kk++) {
                s16x8 a = zfrag;
                if (kk < 3 || g == 0)
                    a = *(const s16x8*)&xbw[(mt * 16 + c16) * 104 + kk * 32 + g * 8];
                a1f[mt][kk] = a;
            }
        SB();

        // LN_c stats from raw h_token (a1f regs): per tok = c16 (within mt tile)
        float rs_r[2][4], rm_r[2][4];
        {
            float mA[2], rA[2];
            #pragma unroll
            for (int mt = 0; mt < 2; mt++) {
                float s = 0.f, s2 = 0.f;
                #pragma unroll
                for (int kk = 0; kk < 4; kk++)
                    #pragma unroll
                    for (int i = 0; i < 8; i++) {
                        float f = bf2f((unsigned short)a1f[mt][kk][i]);
                        s += f;
                        s2 = fmaf(f, f, s2);
                    }
                s  += __shfl_xor(s, 16);  s  += __shfl_xor(s, 32);
                s2 += __shfl_xor(s2, 16); s2 += __shfl_xor(s2, 32);
                float m = s * 0.01f;
                float var = fmaxf(s2 * 0.01f - m * m, 0.f);
                mA[mt] = m;
                rA[mt] = rsqrtf(var + 1e-5f);
            }
            #pragma unroll
            for (int mt = 0; mt < 2; mt++)
                #pragma unroll
                for (int jj = 0; jj < 4; jj++) {
                    int src = g * 4 + jj;
                    float mm = __shfl(mA[mt], src);
                    float rr = __shfl(rA[mt], src);
                    rs_r[mt][jj] = rr;
                    rm_r[mt][jj] = rr * mm;
                }
        }

        #pragma unroll
        for (int a = 0; a < 2; a++)
            #pragma unroll
            for (int c = 0; c < 7; c++) acc2[a][c] = zacc;

        // pipelined: iteration hc computes ch1[hc] -> cbw[hc&1]; ch2 consumes chunk hc-1
        for (int hc = 0; hc < 13; hc++) {
            unsigned short* cw = (hc & 1) ? cbw1 : cbw0;
            f32x4 acc1[2][2];
            float Sg[2], Bp[2];
            #pragma unroll
            for (int a = 0; a < 2; a++) { acc1[a][0] = zacc; acc1[a][1] = zacc; }
            #pragma unroll
            for (int ntl = 0; ntl < 2; ntl++) {
                int ntg = hc * 2 + ntl;
                if (ntg < 25) {
                    int h = ntg * 16 + c16;
                    Sg[ntl] = Sg1[h];
                    Bp[ntl] = b1p[h];
                    #pragma unroll
                    for (int kk = 0; kk < 4; kk++) {
                        s16x8 bfr = wg1f_v[(kk * 25 + ntg) * 64 + l];
                        #pragma unroll
                        for (int mt = 0; mt < 2; mt++)
                            acc1[mt][ntl] = __builtin_amdgcn_mfma_f32_16x16x32_bf16(a1f[mt][kk], bfr, acc1[mt][ntl], 0, 0, 0);
                    }
                }
            }
            #pragma unroll
            for (int ntl = 0; ntl < 2; ntl++) {
                int ntg = hc * 2 + ntl;
                if (ntg < 25) {
                    #pragma unroll
                    for (int mt = 0; mt < 2; mt++)
                        #pragma unroll
                        for (int jj = 0; jj < 4; jj++) {
                            int row = mt * 16 + g * 4 + jj;
                            float h1 = fmaf(rs_r[mt][jj], acc1[mt][ntl][jj],
                                            fmaf(-rm_r[mt][jj], Sg[ntl], Bp[ntl]));
                            cw[row * 40 + ntl * 16 + c16] = cvt_bf16(gelu(h1));
                        }
                }
            }
            SB();
            if (hc > 0) {   // consume previous chunk (write->read gap spans a full iteration)
                unsigned short* cr = (hc & 1) ? cbw0 : cbw1;
                s16x8 a2f[2];
                #pragma unroll
                for (int mt = 0; mt < 2; mt++)
                    a2f[mt] = *(const s16x8*)&cr[(mt * 16 + c16) * 40 + g * 8];
                #pragma unroll
                for (int nt2 = 0; nt2 < 7; nt2++) {
                    s16x8 b2f = w2f_v[((hc - 1) * 7 + nt2) * 64 + l];
                    #pragma unroll
                    for (int mt = 0; mt < 2; mt++)
                        acc2[mt][nt2] = __builtin_amdgcn_mfma_f32_16x16x32_bf16(a2f[mt], b2f, acc2[mt][nt2], 0, 0, 0);
                }
            }
            SB();
        }
        {   // tail: chunk 12 (in cbw0)
            s16x8 a2f[2];
            #pragma unroll
            for (int mt = 0; mt < 2; mt++)
                a2f[mt] = *(const s16x8*)&cbw0[(mt * 16 + c16) * 40 + g * 8];
            #pragma unroll
            for (int nt2 = 0; nt2 < 7; nt2++) {
                s16x8 b2f = w2f_v[(12 * 7 + nt2) * 64 + l];
                #pragma unroll
                for (int mt = 0; mt < 2; mt++)
                    acc2[mt][nt2] = __builtin_amdgcn_mfma_f32_16x16x32_bf16(a2f[mt], b2f, acc2[mt][nt2], 0, 0, 0);
            }
            SB();
        }
    }

    // ================= Phase D: h_channel -> LN_h -> mean -> out proj (registers) =================
    #pragma unroll
    for (int nt = 0; nt < 7; nt++) {
        int col = nt * 16 + c16;
        if (col < 100) {
            float bias = ch2_b[col];
            #pragma unroll
            for (int mt = 0; mt < 2; mt++)
                #pragma unroll
                for (int jj = 0; jj < 4; jj++) {
                    int row = mt * 16 + g * 4 + jj;
                    acc2[mt][nt][jj] += bias + bf2f(xbw[row * 104 + col]);
                }
        }
    }
    float m_[2][4], rs_[2][4];
    #pragma unroll
    for (int mt = 0; mt < 2; mt++)
        #pragma unroll
        for (int jj = 0; jj < 4; jj++) {
            float s = 0.f, s2 = 0.f;
            #pragma unroll
            for (int nt = 0; nt < 7; nt++) {
                float v = acc2[mt][nt][jj];
                s += v;
                s2 = fmaf(v, v, s2);
            }
            #pragma unroll
            for (int msk = 1; msk < 16; msk <<= 1) {
                s  += __shfl_xor(s, msk);
                s2 += __shfl_xor(s2, msk);
            }
            float m = s * 0.01f;
            float var = fmaxf(s2 * 0.01f - m * m, 0.f);
            m_[mt][jj]  = m;
            rs_[mt][jj] = rsqrtf(var + 1e-5f);
        }
    float cs[7];
    #pragma unroll
    for (int nt = 0; nt < 7; nt++) cs[nt] = 0.f;
    #pragma unroll
    for (int mt = 0; mt < 2; mt++)
        #pragma unroll
        for (int jj = 0; jj < 4; jj++) {
            int row = mt * 16 + g * 4 + jj;
            if (row < 30) {
                float m = m_[mt][jj], rs = rs_[mt][jj];
                #pragma unroll
                for (int nt = 0; nt < 7; nt++)
                    cs[nt] = fmaf(acc2[mt][nt][jj] - m, rs, cs[nt]);
            }
        }
    #pragma unroll
    for (int nt = 0; nt < 7; nt++) {
        cs[nt] += __shfl_xor(cs[nt], 16);
        cs[nt] += __shfl_xor(cs[nt], 32);
    }
    float* stF = (float*)scrw;     // cbw buffers dead
    if (g == 0) {
        #pragma unroll
        for (int nt = 0; nt < 7; nt++) {
            int col = nt * 16 + c16;
            if (col < 100)
                stF[col] = ln_h_g[col] * cs[nt] * (1.0f / 30.0f) + ln_h_b[col];
        }
    }
    SB();
    #pragma unroll
    for (int p = 0; p < 2; p++) {
        int o = p * 64 + l;
        if (o < 100 && node < N) {
            float a = out_b[o];
            const float* wr = out_w + o * 100;
            #pragma unroll
            for (int c = 0; c < 100; c += 4) {
                float4 w4 = *(const float4*)(wr + c);
                f32x4 t4 = *(const f32x4*)&stF[c];
                a += w4.x * t4[0] + w4.y * t4[1] + w4.z * t4[2] + w4.w * t4[3];
            }
            out[(size_t)node * 100 + o] = a;
        }
    }
}

// ---------------------------------------------------------------- launch

extern "C" void kernel_launch(void* const* d_in, const int* in_sizes, int n_in,
                              void* d_out, int out_size, void* d_ws, size_t ws_size,
                              hipStream_t stream) {
    const float* edge_attr  = (const float*)d_in[0];
    const float* edge_time  = (const float*)d_in[1];
    const int*   node_batch = (const int*)d_in[2];
    const float* head_w = (const float*)d_in[4];
    const float* head_b = (const float*)d_in[5];
    const float* ln_t_g = (const float*)d_in[6];
    const float* ln_t_b = (const float*)d_in[7];
    const float* tok1_w = (const float*)d_in[8];
    const float* tok1_b = (const float*)d_in[9];
    const float* tok2_w = (const float*)d_in[10];
    const float* tok2_b = (const float*)d_in[11];
    const float* ln_c_g = (const float*)d_in[12];
    const float* ln_c_b = (const float*)d_in[13];
    const float* ch1_w  = (const float*)d_in[14];
    const float* ch1_b  = (const float*)d_in[15];
    const float* ch2_w  = (const float*)d_in[16];
    const float* ch2_b  = (const float*)d_in[17];
    const float* ln_h_g = (const float*)d_in[18];
    const float* ln_h_b = (const float*)d_in[19];
    const float* out_w  = (const float*)d_in[20];
    const float* out_b  = (const float*)d_in[21];
    float* out = (float*)d_out;

    const int E = in_sizes[2];
    const int N = out_size / HIDC;

    int* cnt     = (int*)d_ws;                            // N
    int* cursor  = cnt + N;                               // N
    int* offsets = cursor + N;                            // N
    int* order   = offsets + N;                           // E
    int* sel     = order + E;                             // N*K
    unsigned short* wf = (unsigned short*)(sel + (size_t)N * KTOK);  // 128000 u16
    float* Sg1 = (float*)(wf + 128000);                   // 400
    float* b1p = Sg1 + 400;                               // 400
    int*   bsum = (int*)(b1p + 400);                      // <=64

    const int nbk = (N + 1023) / 1024;

    hipMemsetAsync(cnt, 0, (size_t)2 * N * sizeof(int), stream);
    count_kernel<<<(E + 255) / 256, 256, 0, stream>>>(node_batch, cnt, E);
    scanA_kernel<<<nbk, 1024, 0, stream>>>(cnt, offsets, bsum, N);
    scanB_kernel<<<1, 64, 0, stream>>>(bsum, nbk);
    scanC_kernel<<<(N + 255) / 256, 256, 0, stream>>>(offsets, bsum, N);
    fill_kernel<<<(E + 255) / 256, 256, 0, stream>>>(node_batch, cursor, offsets, order, E);
    select_kernel<<<(N + 255) / 256, 256, 0, stream>>>(cnt, offsets, order, sel, N);
    prep_kernel<<<502, 256, 0, stream>>>(head_w, ch1_w, ch2_w, tok1_w, tok2_w,
                                         ln_c_g, ln_c_b, ch1_b, wf, Sg1, b1p);
    fused_node_kernel<<<(N + 1) / 2, 128, 0, stream>>>(
        edge_attr, edge_time, sel, wf, head_b,
        ln_t_g, ln_t_b, tok1_b, tok2_b, Sg1, b1p,
        ch2_b, ln_h_g, ln_h_b, out_w, out_b, out, N);
}

// Round 11
// 1049.744 us; speedup vs baseline: 1.6302x; 1.0137x over previous
//
#include <hip/hip_runtime.h>
#include <math.h>

#define KTOK 30
#define HIDC 100
// DS-ordering barrier: VALU/SALU/MFMA/VMEM may cross (prefetch + overlap),
// DS reads/writes may NOT (preserves wave-local LDS handoff order).
#define SBD() __builtin_amdgcn_sched_barrier(0x7F)
#define CEXP 0.33554829241286486f

typedef short s16x8 __attribute__((ext_vector_type(8)));
typedef float f32x4 __attribute__((ext_vector_type(4)));

// ---------------------------------------------------------------- helpers
__device__ __forceinline__ unsigned cvt_pk_bf16(float lo, float hi) {
    unsigned r;
    asm("v_cvt_pk_bf16_f32 %0, %1, %2" : "=v"(r) : "v"(lo), "v"(hi));
    return r;
}
__device__ __forceinline__ unsigned short cvt_bf16(float x) {
    unsigned r;
    asm("v_cvt_pk_bf16_f32 %0, %1, 0" : "=v"(r) : "v"(x));
    return (unsigned short)r;
}
__device__ __forceinline__ float bf2f(unsigned short h) {
    return __uint_as_float(((unsigned)h) << 16);
}
__device__ __forceinline__ float exp2_fast(float x) {
    float r;
    asm("v_exp_f32 %0, %1" : "=v"(r) : "v"(x));
    return r;
}
__device__ __forceinline__ float cos_rev(float rev) {   // input in revolutions, |rev|<1
    float r;
    asm("v_cos_f32 %0, %1" : "=v"(r) : "v"(rev));
    return r;
}
__device__ __forceinline__ unsigned short f2bf(float f) {
    unsigned u = __float_as_uint(f);
    unsigned r = (u + 0x7FFFu + ((u >> 16) & 1u)) >> 16;
    return (unsigned short)r;
}
// Transcendental-free GELU: gelu(x) = 0.5x(1+t), t = med3(xc*(a+b s+c s^2+d s^3),-1,1),
// xc = clamp(x,+-2.75) (P(2.75)~1.003 -> clamp makes tails EXACT: gelu->x / 0).
// Fit to tanh-form gelu at x={0.75,1.5,2.25,2.9}; |err|<~0.01 only near |x|~2.7;
// gelu outputs feed matmuls with 0.05-scale weights -> negligible output impact.
__device__ __forceinline__ float gelu(float x) {
    float xc = fminf(fmaxf(x, -2.75f), 2.75f);
    float s = xc * xc;
    float q = fmaf(s, -0.00059132f, 0.0132267f);
    q = fmaf(q, s, -0.122945f);
    q = fmaf(q, s, 0.793839f);
    float p = xc * q;
    float t = __builtin_amdgcn_fmed3f(p, -1.0f, 1.0f);
    float hx = 0.5f * x;
    return fmaf(hx, t, hx);
}

// ---------------------------------------------------------------- selection pipeline
__global__ void count_kernel(const int* __restrict__ nb, int* __restrict__ cnt, int E) {
    int e = blockIdx.x * blockDim.x + threadIdx.x;
    if (e < E) atomicAdd(&cnt[nb[e]], 1);
}

__global__ void scanA_kernel(const int* __restrict__ cnt, int* __restrict__ offsets,
                             int* __restrict__ bsum, int n) {
    __shared__ int sd[1024];
    int tid = threadIdx.x;
    int i = blockIdx.x * 1024 + tid;
    int v = (i < n) ? cnt[i] : 0;
    sd[tid] = v;
    __syncthreads();
    for (int off = 1; off < 1024; off <<= 1) {
        int tv = (tid >= off) ? sd[tid - off] : 0;
        __syncthreads();
        sd[tid] += tv;
        __syncthreads();
    }
    if (i < n) offsets[i] = sd[tid] - v;            // block-local exclusive
    if (tid == 1023) bsum[blockIdx.x] = sd[1023];   // block total
}

__global__ void scanB_kernel(int* __restrict__ bsum, int nbk) {
    if (threadIdx.x == 0 && blockIdx.x == 0) {
        int run = 0;
        for (int b = 0; b < nbk; b++) { int tv = bsum[b]; bsum[b] = run; run += tv; }
    }
}

__global__ void scanC_kernel(int* __restrict__ offsets, const int* __restrict__ bsum, int n) {
    int i = blockIdx.x * blockDim.x + threadIdx.x;
    if (i < n) offsets[i] += bsum[i >> 10];
}

__global__ void fill_kernel(const int* __restrict__ nb, int* __restrict__ cursor,
                            const int* __restrict__ offsets, int* __restrict__ order, int E) {
    int e = blockIdx.x * blockDim.x + threadIdx.x;
    if (e >= E) return;
    int n = nb[e];
    int p = atomicAdd(&cursor[n], 1);
    order[offsets[n] + p] = e;
}

__global__ void select_kernel(const int* __restrict__ cnt, const int* __restrict__ offsets,
                              const int* __restrict__ order, int* __restrict__ sel, int N) {
    int node = blockIdx.x * blockDim.x + threadIdx.x;
    if (node >= N) return;
    int c = cnt[node];
    int off = offsets[node];
    int top[KTOK];
    int m = 0;
    for (int i = 0; i < c; i++) {
        int e = order[off + i];
        if (m < KTOK) {
            int j = m++;
            while (j > 0 && top[j - 1] > e) { top[j] = top[j - 1]; j--; }
            top[j] = e;
        } else if (e < top[KTOK - 1]) {
            int j = KTOK - 1;
            while (j > 0 && top[j - 1] > e) { top[j] = top[j - 1]; j--; }
            top[j] = e;
        }
    }
    for (int p = 0; p < KTOK; p++) sel[node * KTOK + p] = (p < m) ? top[p] : -1;
}

// ---------------------------------------------------------------- weight fragment prep
// B-frag (16x16x32): lane l elem i holds B[kt*32+(l>>4)*8+i][nt*16+(l&15)]
// wf: headWf[8][7][64][8]@0 ; wg1f(=ch1_w*ln_c_g)[4][25][64][8]@28672 ;
//     w2f[13][7][64][8]@79872 ; tok1f[64][8]@126464 ; tok2f[2][64][8]@126976
// extras (f32): Sg1[400] = sum_k ch1_w*g ; b1p[400] = sum_k ch1_w*b + ch1_b
__global__ void prep_kernel(const float* __restrict__ head_w, const float* __restrict__ ch1_w,
                            const float* __restrict__ ch2_w, const float* __restrict__ tok1_w,
                            const float* __restrict__ tok2_w,
                            const float* __restrict__ ln_c_g, const float* __restrict__ ln_c_b,
                            const float* __restrict__ ch1_b,
                            unsigned short* __restrict__ wf,
                            float* __restrict__ Sg1, float* __restrict__ b1p) {
    int i = blockIdx.x * blockDim.x + threadIdx.x;
    if (i >= 128000) {
        int h = i - 128000;
        if (h < 400) {
            float sg = 0.f, sb = 0.f;
            for (int k = 0; k < 100; k++) {
                float w = ch1_w[h * 100 + k];
                sg += w * ln_c_g[k];
                sb += w * ln_c_b[k];
            }
            Sg1[h] = sg;
            b1p[h] = sb + ch1_b[h];
        }
        return;
    }
    float val = 0.0f;
    if (i < 28672) {
        int ii = i & 7, lane = (i >> 3) & 63, rest = i >> 9;
        int nt = rest % 7, kt = rest / 7;
        int k = kt * 32 + ((lane >> 4) << 3) + ii;
        int n = nt * 16 + (lane & 15);
        if (k < 200 && n < 100) val = head_w[n * 200 + k];
    } else if (i < 79872) {
        int j = i - 28672;
        int ii = j & 7, lane = (j >> 3) & 63, rest = j >> 9;
        int nt = rest % 25, kt = rest / 25;
        int k = kt * 32 + ((lane >> 4) << 3) + ii;
        int n = nt * 16 + (lane & 15);
        if (k < 100) val = ch1_w[n * 100 + k] * ln_c_g[k];
    } else if (i < 126464) {
        int j = i - 79872;
        int ii = j & 7, lane = (j >> 3) & 63, rest = j >> 9;
        int nt = rest % 7, kt = rest / 7;
        int k = kt * 32 + ((lane >> 4) << 3) + ii;
        int n = nt * 16 + (lane & 15);
        if (k < 400 && n < 100) val = ch2_w[n * 400 + k];
    } else if (i < 126976) {
        int j = i - 126464;
        int ii = j & 7, lane = (j >> 3) & 63;
        int k = ((lane >> 4) << 3) + ii;
        int n = lane & 15;
        if (k < 30 && n < 15) val = tok1_w[n * 30 + k];
    } else {
        int j = i - 126976;
        int ii = j & 7, lane = (j >> 3) & 63, nt = j >> 9;
        int k = ((lane >> 4) << 3) + ii;
        int n = nt * 16 + (lane & 15);
        if (k < 15 && n < 30) val = tok2_w[n * 15 + k];
    }
    wf[i] = f2bf(val);
}

// ---------------------------------------------------------------- fused per-node forward
// 2 nodes/block, 1 wave/node, zero __syncthreads. LDS/block ~23.5KB.
// waves_per_eu=3 (VGPR budget 168; (128,4) spilled catastrophically in r8).
// sched_barrier(0x7F): DS order pinned, everything else free to overlap/prefetch.
__global__ __launch_bounds__(128, 3) void fused_node_kernel(
    const float* __restrict__ edge_attr, const float* __restrict__ edge_time,
    const int* __restrict__ sel, const unsigned short* __restrict__ wf,
    const float* __restrict__ head_b,
    const float* __restrict__ ln_t_g, const float* __restrict__ ln_t_b,
    const float* __restrict__ tok1_b, const float* __restrict__ tok2_b,
    const float* __restrict__ Sg1, const float* __restrict__ b1p,
    const float* __restrict__ ch2_b,
    const float* __restrict__ ln_h_g, const float* __restrict__ ln_h_b,
    const float* __restrict__ out_w, const float* __restrict__ out_b,
    float* __restrict__ out, int N) {

    __shared__ __align__(16) unsigned short xb2[2][32 * 104];  // x -> h_token (6656 B/wave)
    __shared__ __align__(16) unsigned short scr2[2][2560];     // scatter/y/cbw-dbuf/stF (5120 B/wave)

    const int t = threadIdx.x;
    const int wv = t >> 6, l = t & 63;
    const int g = l >> 4, c16 = l & 15;
    unsigned short* xbw = xb2[wv];
    unsigned short* scrw = scr2[wv];
    char* scrb = (char*)scrw;
    const int node = blockIdx.x * 2 + wv;

    const s16x8 zfrag = {0, 0, 0, 0, 0, 0, 0, 0};
    const f32x4 zacc = {0.f, 0.f, 0.f, 0.f};

    const s16x8* headWf_v = (const s16x8*)(wf);
    const s16x8* wg1f_v   = (const s16x8*)(wf + 28672);
    const s16x8* w2f_v    = (const s16x8*)(wf + 79872);
    const s16x8* tok1f_v  = (const s16x8*)(wf + 126464);
    const s16x8* tok2f_v  = (const s16x8*)(wf + 126976);

    // ---- per-lane edge info (no LDS)
    int eload = (l < KTOK && node < N) ? sel[node * KTOK + l] : -1;
    unsigned long long vmask = __ballot(eload >= 0);   // bit r = validity of token row r
    int e0 = __shfl(eload, c16);
    int e1 = __shfl(eload, 16 + c16);
    float tt0 = (e0 >= 0) ? edge_time[e0] : 0.f;
    float tt1 = (e1 >= 0) ? edge_time[e1] : 0.f;
    const float INV2PI = 0.15915494309189535f;
    float Trev0 = tt0 * INV2PI, Trev1 = tt1 * INV2PI;
    const float* ab0 = edge_attr + (size_t)(e0 < 0 ? 0 : e0) * 100;
    const float* ab1 = edge_attr + (size_t)(e1 < 0 ? 0 : e1) * 100;

    // ================= Phase A: head GEMM, A-frags built in registers =================
    f32x4 hacc[2][7];
    #pragma unroll
    for (int a = 0; a < 2; a++)
        #pragma unroll
        for (int c = 0; c < 7; c++) hacc[a][c] = zacc;

    #pragma unroll
    for (int kc = 0; kc < 4; kc++) {
        s16x8 af[2][2];
        #pragma unroll
        for (int mt = 0; mt < 2; mt++) {
            const float Trev = mt ? Trev1 : Trev0;
            const float* abm = mt ? ab1 : ab0;
            #pragma unroll
            for (int kk = 0; kk < 2; kk++) {
                const int kb0 = kc * 64 + kk * 32;   // compile-time
                if (kb0 >= 224) { af[mt][kk] = zfrag; continue; }   // k>=200 all-zero block
                union { s16x8 v; unsigned u[4]; } r;
                if (kb0 + 32 <= 100) {
                    // pure temporal: IN[k] = cos(t * rho^k), rho^k in revolutions
                    float Ab = Trev * exp2_fast(-CEXP * (float)(kb0 + g * 8));
                    #pragma unroll
                    for (int i2 = 0; i2 < 8; i2 += 2) {
                        float v0 = cos_rev(Ab * exp2f(-CEXP * (float)i2));
                        float v1 = cos_rev(Ab * exp2f(-CEXP * (float)(i2 + 1)));
                        r.u[i2 >> 1] = cvt_pk_bf16(v0, v1);
                    }
                } else if (kb0 == 96) {
                    // mixed: g0 has k 96..103 (4 cos + 4 attr), g>=1 all attr
                    int aoff = kb0 + g * 8 - 100;
                    int ac = aoff < 0 ? 0 : aoff;           // multiples of 4 -> aligned
                    const float* ap = abm + ac;
                    float4 A0 = *(const float4*)ap;
                    float4 A1 = *(const float4*)(ap + 4);
                    float fa[8] = {A0.x, A0.y, A0.z, A0.w, A1.x, A1.y, A1.z, A1.w};
                    float Ab = Trev * exp2_fast(-CEXP * (float)(kb0 + g * 8));
                    #pragma unroll
                    for (int i2 = 0; i2 < 8; i2 += 2) {
                        float cc0 = cos_rev(Ab * exp2f(-CEXP * (float)i2));
                        float cc1 = cos_rev(Ab * exp2f(-CEXP * (float)(i2 + 1)));
                        float a0 = (g == 0) ? ((i2 >= 4) ? fa[(i2 >= 4) ? i2 - 4 : 0] : 0.f) : fa[i2];
                        float a1 = (g == 0) ? ((i2 + 1 >= 4) ? fa[(i2 + 1 >= 4) ? i2 - 3 : 0] : 0.f) : fa[i2 + 1];
                        int k0 = kb0 + g * 8 + i2;
                        float v0 = (k0 < 100) ? cc0 : a0;
                        float v1 = (k0 + 1 < 100) ? cc1 : a1;
                        r.u[i2 >> 1] = cvt_pk_bf16(v0, v1);
                    }
                } else if (kb0 <= 160) {
                    // pure attr
                    int ac = kb0 + g * 8 - 100;
                    const float* ap = abm + ac;
                    float4 A0 = *(const float4*)ap;
                    float4 A1 = *(const float4*)(ap + 4);
                    r.u[0] = cvt_pk_bf16(A0.x, A0.y);
                    r.u[1] = cvt_pk_bf16(A0.z, A0.w);
                    r.u[2] = cvt_pk_bf16(A1.x, A1.y);
                    r.u[3] = cvt_pk_bf16(A1.z, A1.w);
                } else {
                    // kb0 == 192: attr tail + zeros (k>=200)
                    int aoff = kb0 + g * 8 - 100;
                    int ac = aoff > 92 ? 92 : aoff;
                    const float* ap = abm + ac;
                    float4 A0 = *(const float4*)ap;
                    float4 A1 = *(const float4*)(ap + 4);
                    float fa[8] = {A0.x, A0.y, A0.z, A0.w, A1.x, A1.y, A1.z, A1.w};
                    #pragma unroll
                    for (int i2 = 0; i2 < 8; i2 += 2) {
                        int k0 = kb0 + g * 8 + i2;
                        float v0 = (k0 < 200) ? fa[i2] : 0.f;
                        float v1 = (k0 + 1 < 200) ? fa[i2 + 1] : 0.f;
                        r.u[i2 >> 1] = cvt_pk_bf16(v0, v1);
                    }
                }
                af[mt][kk] = r.v;
            }
        }
        #pragma unroll
        for (int nt = 0; nt < 7; nt++) {
            #pragma unroll
            for (int kk = 0; kk < 2; kk++) {
                if (kc == 3 && kk == 1) continue;   // zero K-block: skip load + MFMA
                s16x8 bf = headWf_v[((kc * 2 + kk) * 7 + nt) * 64 + l];
                #pragma unroll
                for (int mt = 0; mt < 2; mt++)
                    hacc[mt][nt] = __builtin_amdgcn_mfma_f32_16x16x32_bf16(af[mt][kk], bf, hacc[mt][nt], 0, 0, 0);
            }
        }
    }

    // ---- per-lane coefficient caches (loaded AFTER Phase A to keep its reg peak low)
    float g7[7], b7[7], hb7[7];
    #pragma unroll
    for (int nt = 0; nt < 7; nt++) {
        int cc = nt * 16 + c16; if (cc > 99) cc = 99;
        g7[nt] = ln_t_g[cc]; b7[nt] = ln_t_b[cc]; hb7[nt] = head_b[cc];
    }

    // ---- x = mask(hacc + bias); rows with sel<0 and cols>=100 are exact 0
    #pragma unroll
    for (int mt = 0; mt < 2; mt++)
        #pragma unroll
        for (int nt = 0; nt < 7; nt++)
            #pragma unroll
            for (int jj = 0; jj < 4; jj++) {
                int row = mt * 16 + g * 4 + jj;
                bool ok = (((vmask >> row) & 1ull) != 0) && (nt < 6 || c16 < 4);
                hacc[mt][nt][jj] = ok ? (hacc[mt][nt][jj] + hb7[nt]) : 0.f;
            }

    // ---- x-store to xbw [32][104] (+ zero pad cols 100..103)
    #pragma unroll
    for (int mt = 0; mt < 2; mt++)
        #pragma unroll
        for (int nt = 0; nt < 7; nt++)
            #pragma unroll
            for (int jj = 0; jj < 4; jj++) {
                int row = mt * 16 + g * 4 + jj;
                int col = nt * 16 + c16;
                if (col < 100)      xbw[row * 104 + col] = cvt_bf16(hacc[mt][nt][jj]);
                else if (col < 104) xbw[row * 104 + col] = 0;
            }

    // ---- LN_t stats per row (reduce over 16 col-lanes)
    float mv[2][4], rv[2][4];
    #pragma unroll
    for (int mt = 0; mt < 2; mt++)
        #pragma unroll
        for (int jj = 0; jj < 4; jj++) {
            float s = 0.f, s2 = 0.f;
            #pragma unroll
            for (int nt = 0; nt < 7; nt++) {
                float v = hacc[mt][nt][jj];
                s += v;
                s2 = fmaf(v, v, s2);
            }
            #pragma unroll
            for (int msk = 1; msk < 16; msk <<= 1) {
                s  += __shfl_xor(s, msk);
                s2 += __shfl_xor(s2, msk);
            }
            float m = s * 0.01f;
            float var = fmaxf(s2 * 0.01f - m * m, 0.f);
            mv[mt][jj] = m;
            rv[mt][jj] = rsqrtf(var + 1e-5f);
        }

    // ---- scatter normalized LN_t into A-slot layout (2 batches: 4 + 3 nt), read av A-frags
    s16x8 av[7];
    #pragma unroll
    for (int nb = 0; nb < 2; nb++) {
        const int nt0 = nb ? 4 : 0;
        const int ntN = nb ? 3 : 4;
        #pragma unroll
        for (int nn = 0; nn < 4; nn++) {
            if (nn < ntN) {
                int nt = nt0 + nn;
                #pragma unroll
                for (int mt = 0; mt < 2; mt++) {
                    float h0 = fmaf((hacc[mt][nt][0] - mv[mt][0]) * rv[mt][0], g7[nt], b7[nt]);
                    float h1 = fmaf((hacc[mt][nt][1] - mv[mt][1]) * rv[mt][1], g7[nt], b7[nt]);
                    float h2 = fmaf((hacc[mt][nt][2] - mv[mt][2]) * rv[mt][2], g7[nt], b7[nt]);
                    float h3 = fmaf((hacc[mt][nt][3] - mv[mt][3]) * rv[mt][3], g7[nt], b7[nt]);
                    unsigned w0 = cvt_pk_bf16(h0, h1);
                    unsigned w1 = cvt_pk_bf16(h2, h3);
                    int ba = nn * 1024 + (c16 + 32 * mt + 16 * (g >> 1)) * 16 + 8 * (g & 1);
                    *(uint2*)(scrb + ba) = make_uint2(w0, w1);
                }
            }
        }
        SBD();
        #pragma unroll
        for (int nn = 0; nn < 4; nn++) {
            if (nn < ntN)
                av[nt0 + nn] = *(const s16x8*)(scrb + nn * 1024 + l * 16);
        }
        SBD();
    }

    // ================= Phase B: token mixer (batched; per-mt7 y regions) =================
    {
        s16x8 b1 = tok1f_v[l];
        float bias1 = (c16 < 15) ? tok1_b[c16] : 0.f;
        // all 7 tok1 MFMAs + gelu + y-writes first (independent chains)
        #pragma unroll
        for (int mt7 = 0; mt7 < 7; mt7++) {
            f32x4 y = __builtin_amdgcn_mfma_f32_16x16x32_bf16(av[mt7], b1, zacc, 0, 0, 0);
            #pragma unroll
            for (int jj = 0; jj < 4; jj++) {
                int ba = mt7 * 512 + (((g * 4 + jj) + (c16 >> 3) * 16) * 16 + (c16 & 7) * 2);
                *(unsigned short*)(scrb + ba) = cvt_bf16(gelu(y[jj] + bias1));
            }
        }
        SBD();
        s16x8 b2a = tok2f_v[l];
        s16x8 b2b = tok2f_v[64 + l];
        float tb0 = tok2_b[c16];
        float tb1 = (c16 < 14) ? tok2_b[16 + c16] : 0.f;
        #pragma unroll
        for (int mt7 = 0; mt7 < 7; mt7++) {
            s16x8 a2 = zfrag;
            if (g < 2) a2 = *(const s16x8*)(scrb + mt7 * 512 + l * 16);
            f32x4 d0 = __builtin_amdgcn_mfma_f32_16x16x32_bf16(a2, b2a, zacc, 0, 0, 0);
            f32x4 d1 = __builtin_amdgcn_mfma_f32_16x16x32_bf16(a2, b2b, zacc, 0, 0, 0);
            #pragma unroll
            for (int jj = 0; jj < 4; jj++) {
                int chD = mt7 * 16 + g * 4 + jj;
                if (chD < 100) {
                    int idx0 = c16 * 104 + chD;
                    xbw[idx0] = cvt_bf16(bf2f(xbw[idx0]) + d0[jj] + tb0);
                    int tok1i = 16 + c16;
                    if (tok1i < 30) {
                        int idx1 = tok1i * 104 + chD;
                        xbw[idx1] = cvt_bf16(bf2f(xbw[idx1]) + d1[jj] + tb1);
                    }
                }
            }
        }
        SBD();
    }

    // ================= Phase C: ch1 (LN_c folded) -> gelu -> ch2 (cbw double-buffered) =================
    unsigned short* cbw0 = scrw;          // [32][40] u16, 2560 B
    unsigned short* cbw1 = scrw + 1280;   // second buffer, 2560 B
    f32x4 acc2[2][7];
    {
        s16x8 a1f[2][4];
        #pragma unroll
        for (int mt = 0; mt < 2; mt++)
            #pragma unroll
            for (int kk = 0; kk < 4; kk++) {
                s16x8 a = zfrag;
                if (kk < 3 || g == 0)
                    a = *(const s16x8*)&xbw[(mt * 16 + c16) * 104 + kk * 32 + g * 8];
                a1f[mt][kk] = a;
            }
        SBD();

        // LN_c stats from raw h_token (a1f regs): per tok = c16 (within mt tile)
        float rs_r[2][4], rm_r[2][4];
        {
            float mA[2], rA[2];
            #pragma unroll
            for (int mt = 0; mt < 2; mt++) {
                float s = 0.f, s2 = 0.f;
                #pragma unroll
                for (int kk = 0; kk < 4; kk++)
                    #pragma unroll
                    for (int i = 0; i < 8; i++) {
                        float f = bf2f((unsigned short)a1f[mt][kk][i]);
                        s += f;
                        s2 = fmaf(f, f, s2);
                    }
                s  += __shfl_xor(s, 16);  s  += __shfl_xor(s, 32);
                s2 += __shfl_xor(s2, 16); s2 += __shfl_xor(s2, 32);
                float m = s * 0.01f;
                float var = fmaxf(s2 * 0.01f - m * m, 0.f);
                mA[mt] = m;
                rA[mt] = rsqrtf(var + 1e-5f);
            }
            #pragma unroll
            for (int mt = 0; mt < 2; mt++)
                #pragma unroll
                for (int jj = 0; jj < 4; jj++) {
                    int src = g * 4 + jj;
                    float mm = __shfl(mA[mt], src);
                    float rr = __shfl(rA[mt], src);
                    rs_r[mt][jj] = rr;
                    rm_r[mt][jj] = rr * mm;
                }
        }

        #pragma unroll
        for (int a = 0; a < 2; a++)
            #pragma unroll
            for (int c = 0; c < 7; c++) acc2[a][c] = zacc;

        // pipelined: iteration hc computes ch1[hc] -> cbw[hc&1]; ch2 consumes chunk hc-1
        for (int hc = 0; hc < 13; hc++) {
            unsigned short* cw = (hc & 1) ? cbw1 : cbw0;
            f32x4 acc1[2][2];
            float Sg[2], Bp[2];
            #pragma unroll
            for (int a = 0; a < 2; a++) { acc1[a][0] = zacc; acc1[a][1] = zacc; }
            #pragma unroll
            for (int ntl = 0; ntl < 2; ntl++) {
                int ntg = hc * 2 + ntl;
                if (ntg < 25) {
                    int h = ntg * 16 + c16;
                    Sg[ntl] = Sg1[h];
                    Bp[ntl] = b1p[h];
                    #pragma unroll
                    for (int kk = 0; kk < 4; kk++) {
                        s16x8 bfr = wg1f_v[(kk * 25 + ntg) * 64 + l];
                        #pragma unroll
                        for (int mt = 0; mt < 2; mt++)
                            acc1[mt][ntl] = __builtin_amdgcn_mfma_f32_16x16x32_bf16(a1f[mt][kk], bfr, acc1[mt][ntl], 0, 0, 0);
                    }
                }
            }
            #pragma unroll
            for (int ntl = 0; ntl < 2; ntl++) {
                int ntg = hc * 2 + ntl;
                if (ntg < 25) {
                    #pragma unroll
                    for (int mt = 0; mt < 2; mt++)
                        #pragma unroll
                        for (int jj = 0; jj < 4; jj++) {
                            int row = mt * 16 + g * 4 + jj;
                            float h1 = fmaf(rs_r[mt][jj], acc1[mt][ntl][jj],
                                            fmaf(-rm_r[mt][jj], Sg[ntl], Bp[ntl]));
                            cw[row * 40 + ntl * 16 + c16] = cvt_bf16(gelu(h1));
                        }
                }
            }
            SBD();
            if (hc > 0) {   // consume previous chunk (write->read gap spans a full iteration)
                unsigned short* cr = (hc & 1) ? cbw0 : cbw1;
                s16x8 a2f[2];
                #pragma unroll
                for (int mt = 0; mt < 2; mt++)
                    a2f[mt] = *(const s16x8*)&cr[(mt * 16 + c16) * 40 + g * 8];
                #pragma unroll
                for (int nt2 = 0; nt2 < 7; nt2++) {
                    s16x8 b2f = w2f_v[((hc - 1) * 7 + nt2) * 64 + l];
                    #pragma unroll
                    for (int mt = 0; mt < 2; mt++)
                        acc2[mt][nt2] = __builtin_amdgcn_mfma_f32_16x16x32_bf16(a2f[mt], b2f, acc2[mt][nt2], 0, 0, 0);
                }
            }
            SBD();
        }
        {   // tail: chunk 12 (in cbw0)
            s16x8 a2f[2];
            #pragma unroll
            for (int mt = 0; mt < 2; mt++)
                a2f[mt] = *(const s16x8*)&cbw0[(mt * 16 + c16) * 40 + g * 8];
            #pragma unroll
            for (int nt2 = 0; nt2 < 7; nt2++) {
                s16x8 b2f = w2f_v[(12 * 7 + nt2) * 64 + l];
                #pragma unroll
                for (int mt = 0; mt < 2; mt++)
                    acc2[mt][nt2] = __builtin_amdgcn_mfma_f32_16x16x32_bf16(a2f[mt], b2f, acc2[mt][nt2], 0, 0, 0);
            }
            SBD();
        }
    }

    // ================= Phase D: h_channel -> LN_h -> mean -> out proj (registers) =================
    #pragma unroll
    for (int nt = 0; nt < 7; nt++) {
        int col = nt * 16 + c16;
        if (col < 100) {
            float bias = ch2_b[col];
            #pragma unroll
            for (int mt = 0; mt < 2; mt++)
                #pragma unroll
                for (int jj = 0; jj < 4; jj++) {
                    int row = mt * 16 + g * 4 + jj;
                    acc2[mt][nt][jj] += bias + bf2f(xbw[row * 104 + col]);
                }
        }
    }
    float m_[2][4], rs_[2][4];
    #pragma unroll
    for (int mt = 0; mt < 2; mt++)
        #pragma unroll
        for (int jj = 0; jj < 4; jj++) {
            float s = 0.f, s2 = 0.f;
            #pragma unroll
            for (int nt = 0; nt < 7; nt++) {
                float v = acc2[mt][nt][jj];
                s += v;
                s2 = fmaf(v, v, s2);
            }
            #pragma unroll
            for (int msk = 1; msk < 16; msk <<= 1) {
                s  += __shfl_xor(s, msk);
                s2 += __shfl_xor(s2, msk);
            }
            float m = s * 0.01f;
            float var = fmaxf(s2 * 0.01f - m * m, 0.f);
            m_[mt][jj]  = m;
            rs_[mt][jj] = rsqrtf(var + 1e-5f);
        }
    float cs[7];
    #pragma unroll
    for (int nt = 0; nt < 7; nt++) cs[nt] = 0.f;
    #pragma unroll
    for (int mt = 0; mt < 2; mt++)
        #pragma unroll
        for (int jj = 0; jj < 4; jj++) {
            int row = mt * 16 + g * 4 + jj;
            if (row < 30) {
                float m = m_[mt][jj], rs = rs_[mt][jj];
                #pragma unroll
                for (int nt = 0; nt < 7; nt++)
                    cs[nt] = fmaf(acc2[mt][nt][jj] - m, rs, cs[nt]);
            }
        }
    #pragma unroll
    for (int nt = 0; nt < 7; nt++) {
        cs[nt] += __shfl_xor(cs[nt], 16);
        cs[nt] += __shfl_xor(cs[nt], 32);
    }
    float* stF = (float*)scrw;     // cbw buffers dead
    if (g == 0) {
        #pragma unroll
        for (int nt = 0; nt < 7; nt++) {
            int col = nt * 16 + c16;
            if (col < 100)
                stF[col] = ln_h_g[col] * cs[nt] * (1.0f / 30.0f) + ln_h_b[col];
        }
    }
    SBD();
    #pragma unroll
    for (int p = 0; p < 2; p++) {
        int o = p * 64 + l;
        if (o < 100 && node < N) {
            float a = out_b[o];
            const float* wr = out_w + o * 100;
            #pragma unroll
            for (int c = 0; c < 100; c += 4) {
                float4 w4 = *(const float4*)(wr + c);
                f32x4 t4 = *(const f32x4*)&stF[c];
                a += w4.x * t4[0] + w4.y * t4[1] + w4.z * t4[2] + w4.w * t4[3];
            }
            out[(size_t)node * 100 + o] = a;
        }
    }
}

// ---------------------------------------------------------------- launch

extern "C" void kernel_launch(void* const* d_in, const int* in_sizes, int n_in,
                              void* d_out, int out_size, void* d_ws, size_t ws_size,
                              hipStream_t stream) {
    const float* edge_attr  = (const float*)d_in[0];
    const float* edge_time  = (const float*)d_in[1];
    const int*   node_batch = (const int*)d_in[2];
    const float* head_w = (const float*)d_in[4];
    const float* head_b = (const float*)d_in[5];
    const float* ln_t_g = (const float*)d_in[6];
    const float* ln_t_b = (const float*)d_in[7];
    const float* tok1_w = (const float*)d_in[8];
    const float* tok1_b = (const float*)d_in[9];
    const float* tok2_w = (const float*)d_in[10];
    const float* tok2_b = (const float*)d_in[11];
    const float* ln_c_g = (const float*)d_in[12];
    const float* ln_c_b = (const float*)d_in[13];
    const float* ch1_w  = (const float*)d_in[14];
    const float* ch1_b  = (const float*)d_in[15];
    const float* ch2_w  = (const float*)d_in[16];
    const float* ch2_b  = (const float*)d_in[17];
    const float* ln_h_g = (const float*)d_in[18];
    const float* ln_h_b = (const float*)d_in[19];
    const float* out_w  = (const float*)d_in[20];
    const float* out_b  = (const float*)d_in[21];
    float* out = (float*)d_out;

    const int E = in_sizes[2];
    const int N = out_size / HIDC;

    int* cnt     = (int*)d_ws;                            // N
    int* cursor  = cnt + N;                               // N
    int* offsets = cursor + N;                            // N
    int* order   = offsets + N;                           // E
    int* sel     = order + E;                             // N*K
    unsigned short* wf = (unsigned short*)(sel + (size_t)N * KTOK);  // 128000 u16
    float* Sg1 = (float*)(wf + 128000);                   // 400
    float* b1p = Sg1 + 400;                               // 400
    int*   bsum = (int*)(b1p + 400);                      // <=64

    const int nbk = (N + 1023) / 1024;

    hipMemsetAsync(cnt, 0, (size_t)2 * N * sizeof(int), stream);
    count_kernel<<<(E + 255) / 256, 256, 0, stream>>>(node_batch, cnt, E);
    scanA_kernel<<<nbk, 1024, 0, stream>>>(cnt, offsets, bsum, N);
    scanB_kernel<<<1, 64, 0, stream>>>(bsum, nbk);
    scanC_kernel<<<(N + 255) / 256, 256, 0, stream>>>(offsets, bsum, N);
    fill_kernel<<<(E + 255) / 256, 256, 0, stream>>>(node_batch, cursor, offsets, order, E);
    select_kernel<<<(N + 255) / 256, 256, 0, stream>>>(cnt, offsets, order, sel, N);
    prep_kernel<<<502, 256, 0, stream>>>(head_w, ch1_w, ch2_w, tok1_w, tok2_w,
                                         ln_c_g, ln_c_b, ch1_b, wf, Sg1, b1p);
    fused_node_kernel<<<(N + 1) / 2, 128, 0, stream>>>(
        edge_attr, edge_time, sel, wf, head_b,
        ln_t_g, ln_t_b, tok1_b, tok2_b, Sg1, b1p,
        ch2_b, ln_h_g, ln_h_b, out_w, out_b, out, N);
}